// Round 1
// 899.882 us; speedup vs baseline: 1.0714x; 1.0714x over previous
//
#include <hip/hip_runtime.h>
#include <math.h>

// Problem constants (fixed by the reference)
#define BB    8
#define LL    2048
#define DMOD  1024
#define DI    2048
#define NST   16
#define MR    (BB*LL)   // 16384 rows
// scan chunking
#define NCH   16
#define CLEN  128       // NCH*CLEN == LL
#define XDW   36        // padded xdbl row: [dt, pad,pad,pad, B0..15, C0..15]

typedef unsigned short bf16_t;
typedef __attribute__((ext_vector_type(8))) __bf16 bf16x8;
typedef __attribute__((ext_vector_type(4))) float  f32x4;

__device__ __forceinline__ float b2f(bf16_t u) {
  return __uint_as_float(((unsigned int)u) << 16);
}
__device__ __forceinline__ bf16_t f2b(float f) {
  unsigned int u = __float_as_uint(f);
  unsigned int r = (u + 0x7FFFu + ((u >> 16) & 1u)) >> 16;  // RNE
  return (bf16_t)r;
}

__device__ __forceinline__ void cstore(float* p, float v)  { *p = v; }
__device__ __forceinline__ void cstore(bf16_t* p, float v) { *p = f2b(v); }

// async global->LDS, 16B per lane; LDS dest = wave-uniform base + lane*16
__device__ __forceinline__ void gld16(const bf16_t* g, bf16_t* l) {
  __builtin_amdgcn_global_load_lds(
      (const __attribute__((address_space(1))) unsigned int*)g,
      (__attribute__((address_space(3))) unsigned int*)l, 16, 0, 0);
}

// softplus via 2 HW transcendentals (abs err ~1e-7, fine vs 5.5e-4 budget)
__device__ __forceinline__ float softplus(float x) {
  return (x > 20.f) ? x : __logf(1.f + __expf(x));
}
__device__ __forceinline__ float silu(float z) {
  return z * __builtin_amdgcn_rcpf(1.f + __expf(-z));
}

// ---------------------------------------------------------------------------
// fp32 -> bf16 convert (vectorized x4)
// ---------------------------------------------------------------------------
__global__ __launch_bounds__(256) void cvt_bf16(
    const float* __restrict__ in, bf16_t* __restrict__ out, int n4)
{
  int i = blockIdx.x * 256 + threadIdx.x;
  if (i >= n4) return;
  float4 v = ((const float4*)in)[i];
  ushort4 u;
  u.x = f2b(v.x); u.y = f2b(v.y); u.z = f2b(v.z); u.w = f2b(v.w);
  ((ushort4*)out)[i] = u;
}

// W_x [33,2048] fp32 -> padded bf16 [64,2048] (rows 33..63 zero)
__global__ __launch_bounds__(256) void cvt_wx(
    const float* __restrict__ W_x, bf16_t* __restrict__ Wx_bf)
{
  int i = blockIdx.x * 256 + threadIdx.x;   // 64*2048 = 131072
  int j = i >> 11;
  Wx_bf[i] = (j < 33) ? f2b(W_x[i]) : (bf16_t)0;
}

// ---------------------------------------------------------------------------
// MFMA GEMM NT: C[M,N] = A[M,K] * B[N,K]^T, bf16 inputs, fp32 acc.
// 128x128 tile, BK=32, 256 thr (4 waves), 4x4 16x16x32 per wave.
// ---------------------------------------------------------------------------
template <typename TC>
__global__ __launch_bounds__(256) void mgemm_nt(
    const bf16_t* __restrict__ A, const bf16_t* __restrict__ B,
    TC* __restrict__ C, int N, int K)
{
  __shared__ __align__(16) bf16_t As[128 * 32];
  __shared__ __align__(16) bf16_t Bs[128 * 32];
  const int tid  = threadIdx.x;
  const int wave = tid >> 6;
  const int lane = tid & 63;
  const int m0 = blockIdx.y * 128;
  const int n0 = blockIdx.x * 128;
  const int wm = (wave >> 1) * 64;
  const int wn = (wave & 1) * 64;
  const int fr = lane & 15;
  const int quad = lane >> 4;

  const int srow = wave * 32 + (lane >> 2);
  const int scol = (lane & 3) * 8;
  const bf16_t* Ag0 = A + (size_t)(m0 + srow) * K + scol;
  const bf16_t* Ag1 = Ag0 + (size_t)16 * K;
  const bf16_t* Bg0 = B + (size_t)(n0 + srow) * K + scol;
  const bf16_t* Bg1 = Bg0 + (size_t)16 * K;
  bf16_t* lA0 = As + (wave * 32) * 32;
  bf16_t* lA1 = As + (wave * 32 + 16) * 32;
  bf16_t* lB0 = Bs + (wave * 32) * 32;
  bf16_t* lB1 = Bs + (wave * 32 + 16) * 32;

  f32x4 acc[4][4];
#pragma unroll
  for (int i = 0; i < 4; ++i)
#pragma unroll
    for (int j = 0; j < 4; ++j) acc[i][j] = (f32x4){0.f, 0.f, 0.f, 0.f};

  for (int k0 = 0; k0 < K; k0 += 32) {
    __syncthreads();
    gld16(Ag0 + k0, lA0);
    gld16(Ag1 + k0, lA1);
    gld16(Bg0 + k0, lB0);
    gld16(Bg1 + k0, lB1);
    __syncthreads();

    bf16x8 a[4], b[4];
#pragma unroll
    for (int i = 0; i < 4; ++i)
      a[i] = *(const bf16x8*)&As[(wm + i * 16 + fr) * 32 + quad * 8];
#pragma unroll
    for (int j = 0; j < 4; ++j)
      b[j] = *(const bf16x8*)&Bs[(wn + j * 16 + fr) * 32 + quad * 8];
#pragma unroll
    for (int i = 0; i < 4; ++i)
#pragma unroll
      for (int j = 0; j < 4; ++j)
        acc[i][j] = __builtin_amdgcn_mfma_f32_16x16x32_bf16(a[i], b[j], acc[i][j], 0, 0, 0);
  }

  // D col = lane&15, row = quad*4 + r
#pragma unroll
  for (int i = 0; i < 4; ++i)
#pragma unroll
    for (int j = 0; j < 4; ++j) {
#pragma unroll
      for (int r = 0; r < 4; ++r) {
        int grow = m0 + wm + i * 16 + quad * 4 + r;
        int gcol = n0 + wn + j * 16 + fr;
        cstore(&C[(size_t)grow * N + gcol], acc[i][j][r]);
      }
    }
}

// ---------------------------------------------------------------------------
// x_dbl MFMA GEMM: xdbl[M,36pad] = xs[M,2048] * Wx_bf[64,2048]^T.
// BM=64, BK=64, 4 waves; wave w owns row-tile w, 3 col-tiles. grid = MR/64.
// Output row layout: dt at col 0, B at 4..19, C at 20..35.
// ---------------------------------------------------------------------------
__global__ __launch_bounds__(256) void xdbl_mfma(
    const bf16_t* __restrict__ xs, const bf16_t* __restrict__ Wx_bf,
    float* __restrict__ xdbl)
{
  __shared__ __align__(16) bf16_t As[2 * 64 * 32];
  __shared__ __align__(16) bf16_t Bs[2 * 64 * 32];
  const int tid  = threadIdx.x;
  const int wave = tid >> 6;
  const int lane = tid & 63;
  const int m0 = blockIdx.x * 64;
  const int fr = lane & 15;
  const int quad = lane >> 4;

  const int srow = wave * 16 + (lane >> 2);
  const int scol = (lane & 3) * 8;
  const bf16_t* Ag = xs + (size_t)(m0 + srow) * DI + scol;
  const bf16_t* Bg = Wx_bf + (size_t)srow * DI + scol;
  bf16_t* lA = As + wave * 512;
  bf16_t* lB = Bs + wave * 512;

  f32x4 acc[3];
#pragma unroll
  for (int jt = 0; jt < 3; ++jt) acc[jt] = (f32x4){0.f, 0.f, 0.f, 0.f};

  for (int k0 = 0; k0 < DI; k0 += 64) {
    __syncthreads();
#pragma unroll
    for (int kk = 0; kk < 2; ++kk) {
      gld16(Ag + k0 + kk * 32, lA + kk * 2048);
      gld16(Bg + k0 + kk * 32, lB + kk * 2048);
    }
    __syncthreads();

#pragma unroll
    for (int kk = 0; kk < 2; ++kk) {
      bf16x8 a = *(const bf16x8*)&As[kk * 2048 + (wave * 16 + fr) * 32 + quad * 8];
#pragma unroll
      for (int jt = 0; jt < 3; ++jt) {
        bf16x8 b = *(const bf16x8*)&Bs[kk * 2048 + (jt * 16 + fr) * 32 + quad * 8];
        acc[jt] = __builtin_amdgcn_mfma_f32_16x16x32_bf16(a, b, acc[jt], 0, 0, 0);
      }
    }
  }

#pragma unroll
  for (int jt = 0; jt < 3; ++jt) {
#pragma unroll
    for (int r = 0; r < 4; ++r) {
      int grow = m0 + wave * 16 + quad * 4 + r;
      int j = jt * 16 + fr;
      if (j < 33) {
        int col = (j == 0) ? 0 : (j + 3);
        xdbl[(size_t)grow * XDW + col] = acc[jt][r];
      }
    }
  }
}

// ---------------------------------------------------------------------------
// Causal depthwise conv1d (k=4) + bias + SiLU.  bf16 xz -> bf16 xs.
// ---------------------------------------------------------------------------
__global__ __launch_bounds__(256) void conv_silu(
    const bf16_t* __restrict__ xz, const float* __restrict__ cw,
    const float* __restrict__ cb, bf16_t* __restrict__ xs)
{
  int idx = blockIdx.x * 256 + threadIdx.x;
  int d4 = idx & 511;
  int l  = (idx >> 9) & 2047;
  int b  = idx >> 20;
  int d  = d4 * 4;

  float wch[4][4];
#pragma unroll
  for (int c = 0; c < 4; ++c)
#pragma unroll
    for (int k = 0; k < 4; ++k) wch[c][k] = cw[(d + c) * 4 + k];

  float acc0 = cb[d+0], acc1 = cb[d+1], acc2 = cb[d+2], acc3 = cb[d+3];
  size_t rowbase = ((size_t)b * LL + l) * 4096 + d;
#pragma unroll
  for (int k = 0; k < 4; ++k) {
    if (l - 3 + k >= 0) {
      ushort4 u = *(const ushort4*)(xz + rowbase - (size_t)(3 - k) * 4096);
      acc0 += b2f(u.x) * wch[0][k];
      acc1 += b2f(u.y) * wch[1][k];
      acc2 += b2f(u.z) * wch[2][k];
      acc3 += b2f(u.w) * wch[3][k];
    }
  }
  ushort4 o;
  o.x = f2b(silu(acc0)); o.y = f2b(silu(acc1));
  o.z = f2b(silu(acc2)); o.w = f2b(silu(acc3));
  *(ushort4*)(xs + ((size_t)b * LL + l) * (size_t)DI + d) = o;
}

// ---------------------------------------------------------------------------
// Scan pass 1: per (b, chunk) scan from h=0; ONE channel per thread.
// grid: 1024 = b(8) x chunk(16) x dgroup(8); thread covers d = dg*256+tid.
// Live state = A2[16]+h[16]+~25 scalars ~= 60 VGPR -> no AGPR spill
// (previous 2-ch/thread version needed ~90 regs in a 64-VGPR alloc ->
//  v_accvgpr shuffles inflated VALU issue ~4x).
// P[n] computed as exp2(A2[n]*sum(dt)) -- no per-step product.
// states: [b][c][d][32] fp32 (0..15 P, 16..31 h_end).
// ---------------------------------------------------------------------------
__global__ __launch_bounds__(256) void scan_pass1(
    const float* __restrict__ xdbl, const bf16_t* __restrict__ xs,
    const float* __restrict__ W_dt, const float* __restrict__ b_dt,
    const float* __restrict__ A_log, float* __restrict__ states)
{
  const int bid = blockIdx.x;
  const int dg = bid & 7, c = (bid >> 3) & 15, b = bid >> 7;
  const int d = dg * 256 + threadIdx.x;

  float A2[NST], h[NST];
#pragma unroll
  for (int n = 0; n < NST; ++n) {
    A2[n] = -__expf(A_log[(size_t)d * NST + n]) * 1.44269504f;
    h[n] = 0.f;
  }
  const float wdt = W_dt[d], bdt = b_dt[d];
  float dts = 0.f;

  __shared__ float sx[64 * XDW];
  const size_t rbase = (size_t)b * LL + c * CLEN;

  float xv = b2f(xs[rbase * DI + d]);

  for (int s = 0; s < CLEN; s += 64) {
    __syncthreads();
    const float* xg = xdbl + (rbase + s) * XDW;
    for (int q = threadIdx.x; q < 64 * XDW; q += 256) sx[q] = xg[q];
    __syncthreads();
#pragma unroll 2
    for (int u = 0; u < 64; ++u) {
      int tn = s + u + 1;
      float nx = 0.f;
      if (tn < CLEN) nx = b2f(xs[(rbase + tn) * DI + d]);
      float dtr = sx[u * XDW];
      float dt = softplus(fmaf(dtr, wdt, bdt));
      dts += dt;
      float dx = dt * xv;
      const float4* Bp = (const float4*)&sx[u * XDW + 4];
#pragma unroll
      for (int n4 = 0; n4 < 4; ++n4) {
        float4 Bv = Bp[n4];
        float bb[4] = {Bv.x, Bv.y, Bv.z, Bv.w};
#pragma unroll
        for (int k = 0; k < 4; ++k) {
          int n = n4 * 4 + k;
          h[n] = fmaf(exp2f(dt * A2[n]), h[n], dx * bb[k]);
        }
      }
      xv = nx;
    }
  }
  size_t sb = (((size_t)b * NCH + c) * DI + d) * 32;
#pragma unroll
  for (int n = 0; n < NST; ++n) {
    states[sb + n]      = exp2f(dts * A2[n]);
    states[sb + 16 + n] = h[n];
  }
}

// ---------------------------------------------------------------------------
// Scan pass 2: compose chunk states sequentially; h_init -> P slot (in place).
// ---------------------------------------------------------------------------
__global__ __launch_bounds__(256) void scan_pass2(float* __restrict__ states)
{
  int t = blockIdx.x * 256 + threadIdx.x;    // 8*2048*16 = 262144
  int n = t & 15, d = (t >> 4) & 2047, b = t >> 15;
  float h = 0.f;
  for (int c = 0; c < NCH; ++c) {
    size_t sb = (((size_t)b * NCH + c) * DI + d) * 32;
    float P  = states[sb + n];
    float h0 = states[sb + 16 + n];
    states[sb + n] = h;          // h_init entering chunk c
    h = fmaf(P, h, h0);
  }
}

// ---------------------------------------------------------------------------
// Scan pass 3: re-scan from h_init; y = C.h + D*x; gate SiLU(z); bf16 in place.
// ONE channel per thread, same decomposition as pass 1.
// ---------------------------------------------------------------------------
__global__ __launch_bounds__(256) void scan_pass3(
    const float* __restrict__ xdbl, const bf16_t* __restrict__ xz,
    bf16_t* __restrict__ xs, const float* __restrict__ states,
    const float* __restrict__ W_dt, const float* __restrict__ b_dt,
    const float* __restrict__ A_log, const float* __restrict__ Dp)
{
  const int bid = blockIdx.x;
  const int dg = bid & 7, c = (bid >> 3) & 15, b = bid >> 7;
  const int d = dg * 256 + threadIdx.x;

  float A2[NST], h[NST];
  size_t sb = (((size_t)b * NCH + c) * DI + d) * 32;
#pragma unroll
  for (int n = 0; n < NST; ++n) {
    A2[n] = -__expf(A_log[(size_t)d * NST + n]) * 1.44269504f;
    h[n] = states[sb + n];
  }
  const float wdt = W_dt[d], bdt = b_dt[d];
  const float Dd = Dp[d];

  __shared__ float sx[64 * XDW];
  const size_t rbase = (size_t)b * LL + c * CLEN;

  float xv = b2f(xs[rbase * DI + d]);
  float zv = b2f(xz[rbase * 4096 + DI + d]);

  for (int s = 0; s < CLEN; s += 64) {
    __syncthreads();
    const float* xg = xdbl + (rbase + s) * XDW;
    for (int q = threadIdx.x; q < 64 * XDW; q += 256) sx[q] = xg[q];
    __syncthreads();
#pragma unroll 2
    for (int u = 0; u < 64; ++u) {
      size_t r = rbase + s + u;
      int tn = s + u + 1;
      float nx = 0.f, nz = 0.f;
      if (tn < CLEN) {
        nx = b2f(xs[(rbase + tn) * DI + d]);
        nz = b2f(xz[(rbase + tn) * 4096 + DI + d]);
      }
      float dtr = sx[u * XDW];
      float dt = softplus(fmaf(dtr, wdt, bdt));
      float dx = dt * xv;
      float y = Dd * xv;
      const float4* Bp = (const float4*)&sx[u * XDW + 4];
      const float4* Cp = (const float4*)&sx[u * XDW + 20];
#pragma unroll
      for (int n4 = 0; n4 < 4; ++n4) {
        float4 Bv = Bp[n4];
        float4 Cv = Cp[n4];
        float bb[4] = {Bv.x, Bv.y, Bv.z, Bv.w};
        float cc[4] = {Cv.x, Cv.y, Cv.z, Cv.w};
#pragma unroll
        for (int k = 0; k < 4; ++k) {
          int n = n4 * 4 + k;
          h[n] = fmaf(exp2f(dt * A2[n]), h[n], dx * bb[k]);
          y = fmaf(h[n], cc[k], y);
        }
      }
      xs[r * DI + d] = f2b(y * silu(zv));
      xv = nx; zv = nz;
    }
  }
}

// ---------------------------------------------------------------------------
extern "C" void kernel_launch(void* const* d_in, const int* in_sizes, int n_in,
                              void* d_out, int out_size, void* d_ws, size_t ws_size,
                              hipStream_t stream)
{
  const float* x     = (const float*)d_in[0];
  const float* W_in  = (const float*)d_in[1];
  const float* cw    = (const float*)d_in[2];
  const float* cb    = (const float*)d_in[3];
  const float* W_x   = (const float*)d_in[4];
  const float* W_dt  = (const float*)d_in[5];
  const float* b_dt  = (const float*)d_in[6];
  const float* A_log = (const float*)d_in[7];
  const float* Dp    = (const float*)d_in[8];
  const float* W_out = (const float*)d_in[9];
  float* out = (float*)d_out;

  // ws (proven-safe footprint): xz bf16 [16384,4096] | xs bf16 [16384,2048]
  bf16_t* xz = (bf16_t*)d_ws;
  bf16_t* xs = xz + (size_t)MR * 4096;

  // d_out (64 MiB fp32) as phase-disjoint scratch:
  //   conversions: x_bf [0,32M) | Win_bf [32M,40M) | Wx_bf [40M,40.25M)
  //   scan:        states [0,33.6M) | xdbl [33.6M,36M)  (x_bf/Win_bf dead)
  //   GEMM3 output overwrites everything last.
  bf16_t* x_bf    = (bf16_t*)d_out;
  bf16_t* Win_bf  = x_bf + (size_t)MR * DMOD;
  bf16_t* Wx_bf   = Win_bf + (size_t)4096 * DMOD;
  float*  states  = (float*)d_out;
  float*  xdbl    = states + (size_t)BB * NCH * DI * 32;   // 8.39M floats in
  bf16_t* Wout_bf = xz;   // overlays dead xz after scan pass 3

  // 0) operand conversions
  cvt_bf16<<<(MR*DMOD/4 + 255)/256, 256, 0, stream>>>(x, x_bf, MR*DMOD/4);
  cvt_bf16<<<(4096*DMOD/4 + 255)/256, 256, 0, stream>>>(W_in, Win_bf, 4096*DMOD/4);
  cvt_wx<<<(64*DI)/256, 256, 0, stream>>>(W_x, Wx_bf);
  // 1) xz = x @ W_in^T   (M=16384, N=4096, K=1024) bf16 MFMA
  mgemm_nt<bf16_t><<<dim3(4096/128, MR/128), 256, 0, stream>>>(x_bf, Win_bf, xz, 4096, DMOD);
  // 2) causal depthwise conv + bias + SiLU -> xs (bf16)
  conv_silu<<<(BB*LL*512)/256, 256, 0, stream>>>(xz, cw, cb, xs);
  // 3) x_dbl (padded rows) = xs @ W_x^T (MFMA)
  xdbl_mfma<<<MR/64, 256, 0, stream>>>(xs, Wx_bf, xdbl);
  // 4) chunked selective scan (3 passes) + D*xs + SiLU(z) gate, in place in xs
  scan_pass1<<<BB*NCH*8, 256, 0, stream>>>(xdbl, xs, W_dt, b_dt, A_log, states);
  scan_pass2<<<(BB*DI*NST)/256, 256, 0, stream>>>(states);
  scan_pass3<<<BB*NCH*8, 256, 0, stream>>>(xdbl, xz, xs, states, W_dt, b_dt, A_log, Dp);
  // 5) W_out -> bf16 (dead xz region), then out = gated @ W_out^T
  cvt_bf16<<<(DMOD*DI/4 + 255)/256, 256, 0, stream>>>(W_out, Wout_bf, DMOD*DI/4);
  mgemm_nt<float><<<dim3(DMOD/128, MR/128), 256, 0, stream>>>(xs, Wout_bf, out, DMOD, DI);
}

// Round 2
// 756.623 us; speedup vs baseline: 1.2743x; 1.1893x over previous
//
#include <hip/hip_runtime.h>
#include <math.h>

// Problem constants (fixed by the reference)
#define BB    8
#define LL    2048
#define DMOD  1024
#define DI    2048
#define NST   16
#define MR    (BB*LL)   // 16384 rows
// scan chunking
#define NCH   16
#define CLEN  128       // NCH*CLEN == LL
#define XDW   36        // padded xdbl row: [dt, pad,pad,pad, B0..15, C0..15]

typedef unsigned short bf16_t;
typedef __attribute__((ext_vector_type(8))) __bf16 bf16x8;
typedef __attribute__((ext_vector_type(4))) float  f32x4;

__device__ __forceinline__ float b2f(bf16_t u) {
  return __uint_as_float(((unsigned int)u) << 16);
}
__device__ __forceinline__ bf16_t f2b(float f) {
  unsigned int u = __float_as_uint(f);
  unsigned int r = (u + 0x7FFFu + ((u >> 16) & 1u)) >> 16;  // RNE
  return (bf16_t)r;
}

__device__ __forceinline__ void cstore(float* p, float v)  { *p = v; }
__device__ __forceinline__ void cstore(bf16_t* p, float v) { *p = f2b(v); }

// async global->LDS, 16B per lane; LDS dest = wave-uniform base + lane*16
__device__ __forceinline__ void gld16(const bf16_t* g, bf16_t* l) {
  __builtin_amdgcn_global_load_lds(
      (const __attribute__((address_space(1))) unsigned int*)g,
      (__attribute__((address_space(3))) unsigned int*)l, 16, 0, 0);
}

// softplus via 2 HW transcendentals (abs err ~1e-7, fine vs 5.5e-4 budget)
__device__ __forceinline__ float softplus(float x) {
  return (x > 20.f) ? x : __logf(1.f + __expf(x));
}
__device__ __forceinline__ float silu(float z) {
  return z * __builtin_amdgcn_rcpf(1.f + __expf(-z));
}

// ---------------------------------------------------------------------------
// fp32 -> bf16 convert (vectorized x4)
// ---------------------------------------------------------------------------
__global__ __launch_bounds__(256) void cvt_bf16(
    const float* __restrict__ in, bf16_t* __restrict__ out, int n4)
{
  int i = blockIdx.x * 256 + threadIdx.x;
  if (i >= n4) return;
  float4 v = ((const float4*)in)[i];
  ushort4 u;
  u.x = f2b(v.x); u.y = f2b(v.y); u.z = f2b(v.z); u.w = f2b(v.w);
  ((ushort4*)out)[i] = u;
}

// W_x [33,2048] fp32 -> padded bf16 [64,2048] (rows 33..63 zero)
__global__ __launch_bounds__(256) void cvt_wx(
    const float* __restrict__ W_x, bf16_t* __restrict__ Wx_bf)
{
  int i = blockIdx.x * 256 + threadIdx.x;   // 64*2048 = 131072
  int j = i >> 11;
  Wx_bf[i] = (j < 33) ? f2b(W_x[i]) : (bf16_t)0;
}

// ---------------------------------------------------------------------------
// MFMA GEMM NT: C[M,N] = A[M,K] * B[N,K]^T, bf16 inputs, fp32 acc.
// 128x128 tile, BK=32, 256 thr (4 waves), 4x4 16x16x32 per wave.
// ---------------------------------------------------------------------------
template <typename TC>
__global__ __launch_bounds__(256) void mgemm_nt(
    const bf16_t* __restrict__ A, const bf16_t* __restrict__ B,
    TC* __restrict__ C, int N, int K)
{
  __shared__ __align__(16) bf16_t As[128 * 32];
  __shared__ __align__(16) bf16_t Bs[128 * 32];
  const int tid  = threadIdx.x;
  const int wave = tid >> 6;
  const int lane = tid & 63;
  const int m0 = blockIdx.y * 128;
  const int n0 = blockIdx.x * 128;
  const int wm = (wave >> 1) * 64;
  const int wn = (wave & 1) * 64;
  const int fr = lane & 15;
  const int quad = lane >> 4;

  const int srow = wave * 32 + (lane >> 2);
  const int scol = (lane & 3) * 8;
  const bf16_t* Ag0 = A + (size_t)(m0 + srow) * K + scol;
  const bf16_t* Ag1 = Ag0 + (size_t)16 * K;
  const bf16_t* Bg0 = B + (size_t)(n0 + srow) * K + scol;
  const bf16_t* Bg1 = Bg0 + (size_t)16 * K;
  bf16_t* lA0 = As + (wave * 32) * 32;
  bf16_t* lA1 = As + (wave * 32 + 16) * 32;
  bf16_t* lB0 = Bs + (wave * 32) * 32;
  bf16_t* lB1 = Bs + (wave * 32 + 16) * 32;

  f32x4 acc[4][4];
#pragma unroll
  for (int i = 0; i < 4; ++i)
#pragma unroll
    for (int j = 0; j < 4; ++j) acc[i][j] = (f32x4){0.f, 0.f, 0.f, 0.f};

  for (int k0 = 0; k0 < K; k0 += 32) {
    __syncthreads();
    gld16(Ag0 + k0, lA0);
    gld16(Ag1 + k0, lA1);
    gld16(Bg0 + k0, lB0);
    gld16(Bg1 + k0, lB1);
    __syncthreads();

    bf16x8 a[4], b[4];
#pragma unroll
    for (int i = 0; i < 4; ++i)
      a[i] = *(const bf16x8*)&As[(wm + i * 16 + fr) * 32 + quad * 8];
#pragma unroll
    for (int j = 0; j < 4; ++j)
      b[j] = *(const bf16x8*)&Bs[(wn + j * 16 + fr) * 32 + quad * 8];
#pragma unroll
    for (int i = 0; i < 4; ++i)
#pragma unroll
      for (int j = 0; j < 4; ++j)
        acc[i][j] = __builtin_amdgcn_mfma_f32_16x16x32_bf16(a[i], b[j], acc[i][j], 0, 0, 0);
  }

  // D col = lane&15, row = quad*4 + r
#pragma unroll
  for (int i = 0; i < 4; ++i)
#pragma unroll
    for (int j = 0; j < 4; ++j) {
#pragma unroll
      for (int r = 0; r < 4; ++r) {
        int grow = m0 + wm + i * 16 + quad * 4 + r;
        int gcol = n0 + wn + j * 16 + fr;
        cstore(&C[(size_t)grow * N + gcol], acc[i][j][r]);
      }
    }
}

// ---------------------------------------------------------------------------
// x_dbl MFMA GEMM: xdbl[M,36pad] = xs[M,2048] * Wx_bf[64,2048]^T.
// BM=64, BK=64, 4 waves; wave w owns row-tile w, 3 col-tiles. grid = MR/64.
// Output row layout: dt at col 0, B at 4..19, C at 20..35.
// ---------------------------------------------------------------------------
__global__ __launch_bounds__(256) void xdbl_mfma(
    const bf16_t* __restrict__ xs, const bf16_t* __restrict__ Wx_bf,
    float* __restrict__ xdbl)
{
  __shared__ __align__(16) bf16_t As[2 * 64 * 32];
  __shared__ __align__(16) bf16_t Bs[2 * 64 * 32];
  const int tid  = threadIdx.x;
  const int wave = tid >> 6;
  const int lane = tid & 63;
  const int m0 = blockIdx.x * 64;
  const int fr = lane & 15;
  const int quad = lane >> 4;

  const int srow = wave * 16 + (lane >> 2);
  const int scol = (lane & 3) * 8;
  const bf16_t* Ag = xs + (size_t)(m0 + srow) * DI + scol;
  const bf16_t* Bg = Wx_bf + (size_t)srow * DI + scol;
  bf16_t* lA = As + wave * 512;
  bf16_t* lB = Bs + wave * 512;

  f32x4 acc[3];
#pragma unroll
  for (int jt = 0; jt < 3; ++jt) acc[jt] = (f32x4){0.f, 0.f, 0.f, 0.f};

  for (int k0 = 0; k0 < DI; k0 += 64) {
    __syncthreads();
#pragma unroll
    for (int kk = 0; kk < 2; ++kk) {
      gld16(Ag + k0 + kk * 32, lA + kk * 2048);
      gld16(Bg + k0 + kk * 32, lB + kk * 2048);
    }
    __syncthreads();

#pragma unroll
    for (int kk = 0; kk < 2; ++kk) {
      bf16x8 a = *(const bf16x8*)&As[kk * 2048 + (wave * 16 + fr) * 32 + quad * 8];
#pragma unroll
      for (int jt = 0; jt < 3; ++jt) {
        bf16x8 b = *(const bf16x8*)&Bs[kk * 2048 + (jt * 16 + fr) * 32 + quad * 8];
        acc[jt] = __builtin_amdgcn_mfma_f32_16x16x32_bf16(a, b, acc[jt], 0, 0, 0);
      }
    }
  }

#pragma unroll
  for (int jt = 0; jt < 3; ++jt) {
#pragma unroll
    for (int r = 0; r < 4; ++r) {
      int grow = m0 + wave * 16 + quad * 4 + r;
      int j = jt * 16 + fr;
      if (j < 33) {
        int col = (j == 0) ? 0 : (j + 3);
        xdbl[(size_t)grow * XDW + col] = acc[jt][r];
      }
    }
  }
}

// ---------------------------------------------------------------------------
// Causal depthwise conv1d (k=4) + bias + SiLU.  bf16 xz -> bf16 xs.
// ---------------------------------------------------------------------------
__global__ __launch_bounds__(256) void conv_silu(
    const bf16_t* __restrict__ xz, const float* __restrict__ cw,
    const float* __restrict__ cb, bf16_t* __restrict__ xs)
{
  int idx = blockIdx.x * 256 + threadIdx.x;
  int d4 = idx & 511;
  int l  = (idx >> 9) & 2047;
  int b  = idx >> 20;
  int d  = d4 * 4;

  float wch[4][4];
#pragma unroll
  for (int c = 0; c < 4; ++c)
#pragma unroll
    for (int k = 0; k < 4; ++k) wch[c][k] = cw[(d + c) * 4 + k];

  float acc0 = cb[d+0], acc1 = cb[d+1], acc2 = cb[d+2], acc3 = cb[d+3];
  size_t rowbase = ((size_t)b * LL + l) * 4096 + d;
#pragma unroll
  for (int k = 0; k < 4; ++k) {
    if (l - 3 + k >= 0) {
      ushort4 u = *(const ushort4*)(xz + rowbase - (size_t)(3 - k) * 4096);
      acc0 += b2f(u.x) * wch[0][k];
      acc1 += b2f(u.y) * wch[1][k];
      acc2 += b2f(u.z) * wch[2][k];
      acc3 += b2f(u.w) * wch[3][k];
    }
  }
  ushort4 o;
  o.x = f2b(silu(acc0)); o.y = f2b(silu(acc1));
  o.z = f2b(silu(acc2)); o.w = f2b(silu(acc3));
  *(ushort4*)(xs + ((size_t)b * LL + l) * (size_t)DI + d) = o;
}

// ---------------------------------------------------------------------------
// Scan pass 1: per (b, chunk) scan from h=0; ONE channel per thread.
// grid: 1024 = b(8) x chunk(16) x dgroup(8); thread covers d = dg*256+tid.
//
// FAST PATH: the reference fixes A[d,n] = -(n+1), so
//   exp2(dt*A2[n]) == w^(n+1) with w = exp2(dt*A2[0]).
// One v_exp + 15 muls per timestep instead of 16 v_exp.  Verified per
// thread against A_log at init; block-uniform fallback to the exact
// per-n path otherwise (branch must be block-uniform: both paths
// contain __syncthreads).
// states: [b][c][d][32] fp32 (0..15 P, 16..31 h_end).
// ---------------------------------------------------------------------------
__global__ __launch_bounds__(256) void scan_pass1(
    const float* __restrict__ xdbl, const bf16_t* __restrict__ xs,
    const float* __restrict__ W_dt, const float* __restrict__ b_dt,
    const float* __restrict__ A_log, float* __restrict__ states)
{
  const int bid = blockIdx.x;
  const int dg = bid & 7, c = (bid >> 3) & 15, b = bid >> 7;
  const int d = dg * 256 + threadIdx.x;

  const float A2_0 = -__expf(A_log[(size_t)d * NST]) * 1.44269504f;
  bool ok = true;
#pragma unroll
  for (int n = 1; n < NST; ++n) {
    float a = -__expf(A_log[(size_t)d * NST + n]) * 1.44269504f;
    ok = ok && (fabsf(a - (float)(n + 1) * A2_0) <= 1e-3f * (float)(n + 1));
  }
  __shared__ int s_ok;
  __shared__ float sx[64 * XDW];
  if (threadIdx.x == 0) s_ok = 1;
  __syncthreads();
  if (!ok) s_ok = 0;           // benign race: only 0 is written
  __syncthreads();
  const bool fast = (s_ok != 0);

  float h[NST];
#pragma unroll
  for (int n = 0; n < NST; ++n) h[n] = 0.f;
  const float wdt = W_dt[d], bdt = b_dt[d];
  float dts = 0.f;
  const size_t rbase = (size_t)b * LL + c * CLEN;
  float xv = b2f(xs[rbase * DI + d]);

  if (fast) {
    for (int s = 0; s < CLEN; s += 64) {
      __syncthreads();
      const float* xg = xdbl + (rbase + s) * XDW;
      for (int q = threadIdx.x; q < 64 * XDW; q += 256) sx[q] = xg[q];
      __syncthreads();
#pragma unroll 2
      for (int u = 0; u < 64; ++u) {
        int tn = s + u + 1;
        float nx = 0.f;
        if (tn < CLEN) nx = b2f(xs[(rbase + tn) * DI + d]);
        float dtr = sx[u * XDW];
        float dt = softplus(fmaf(dtr, wdt, bdt));
        dts += dt;
        float dx = dt * xv;
        float wv[NST];
        wv[0] = exp2f(dt * A2_0);
#pragma unroll
        for (int n = 1; n < NST; ++n)
          wv[n] = wv[(n - 1) >> 1] * wv[n - 1 - ((n - 1) >> 1)];  // w^(n+1), depth 4
        const float4* Bp = (const float4*)&sx[u * XDW + 4];
#pragma unroll
        for (int n4 = 0; n4 < 4; ++n4) {
          float4 Bv = Bp[n4];
          float bb[4] = {Bv.x, Bv.y, Bv.z, Bv.w};
#pragma unroll
          for (int k = 0; k < 4; ++k) {
            int n = n4 * 4 + k;
            h[n] = fmaf(wv[n], h[n], dx * bb[k]);
          }
        }
        xv = nx;
      }
    }
    size_t sb = (((size_t)b * NCH + c) * DI + d) * 32;
    float Wv[NST];
    Wv[0] = exp2f(dts * A2_0);
#pragma unroll
    for (int n = 1; n < NST; ++n)
      Wv[n] = Wv[(n - 1) >> 1] * Wv[n - 1 - ((n - 1) >> 1)];
#pragma unroll
    for (int n = 0; n < NST; ++n) {
      states[sb + n]      = Wv[n];
      states[sb + 16 + n] = h[n];
    }
  } else {
    float A2[NST];
#pragma unroll
    for (int n = 0; n < NST; ++n)
      A2[n] = -__expf(A_log[(size_t)d * NST + n]) * 1.44269504f;
    for (int s = 0; s < CLEN; s += 64) {
      __syncthreads();
      const float* xg = xdbl + (rbase + s) * XDW;
      for (int q = threadIdx.x; q < 64 * XDW; q += 256) sx[q] = xg[q];
      __syncthreads();
#pragma unroll 2
      for (int u = 0; u < 64; ++u) {
        int tn = s + u + 1;
        float nx = 0.f;
        if (tn < CLEN) nx = b2f(xs[(rbase + tn) * DI + d]);
        float dtr = sx[u * XDW];
        float dt = softplus(fmaf(dtr, wdt, bdt));
        dts += dt;
        float dx = dt * xv;
        const float4* Bp = (const float4*)&sx[u * XDW + 4];
#pragma unroll
        for (int n4 = 0; n4 < 4; ++n4) {
          float4 Bv = Bp[n4];
          float bb[4] = {Bv.x, Bv.y, Bv.z, Bv.w};
#pragma unroll
          for (int k = 0; k < 4; ++k) {
            int n = n4 * 4 + k;
            h[n] = fmaf(exp2f(dt * A2[n]), h[n], dx * bb[k]);
          }
        }
        xv = nx;
      }
    }
    size_t sb = (((size_t)b * NCH + c) * DI + d) * 32;
#pragma unroll
    for (int n = 0; n < NST; ++n) {
      states[sb + n]      = exp2f(dts * A2[n]);
      states[sb + 16 + n] = h[n];
    }
  }
}

// ---------------------------------------------------------------------------
// Scan pass 2: compose chunk states sequentially; h_init -> P slot (in place).
// ---------------------------------------------------------------------------
__global__ __launch_bounds__(256) void scan_pass2(float* __restrict__ states)
{
  int t = blockIdx.x * 256 + threadIdx.x;    // 8*2048*16 = 262144
  int n = t & 15, d = (t >> 4) & 2047, b = t >> 15;
  float h = 0.f;
  for (int c = 0; c < NCH; ++c) {
    size_t sb = (((size_t)b * NCH + c) * DI + d) * 32;
    float P  = states[sb + n];
    float h0 = states[sb + 16 + n];
    states[sb + n] = h;          // h_init entering chunk c
    h = fmaf(P, h, h0);
  }
}

// ---------------------------------------------------------------------------
// Scan pass 3: re-scan from h_init; y = C.h + D*x; gate SiLU(z); bf16 in place.
// ONE channel per thread; same FAST-path power-chain trick as pass 1.
// ---------------------------------------------------------------------------
__global__ __launch_bounds__(256) void scan_pass3(
    const float* __restrict__ xdbl, const bf16_t* __restrict__ xz,
    bf16_t* __restrict__ xs, const float* __restrict__ states,
    const float* __restrict__ W_dt, const float* __restrict__ b_dt,
    const float* __restrict__ A_log, const float* __restrict__ Dp)
{
  const int bid = blockIdx.x;
  const int dg = bid & 7, c = (bid >> 3) & 15, b = bid >> 7;
  const int d = dg * 256 + threadIdx.x;

  const float A2_0 = -__expf(A_log[(size_t)d * NST]) * 1.44269504f;
  bool ok = true;
#pragma unroll
  for (int n = 1; n < NST; ++n) {
    float a = -__expf(A_log[(size_t)d * NST + n]) * 1.44269504f;
    ok = ok && (fabsf(a - (float)(n + 1) * A2_0) <= 1e-3f * (float)(n + 1));
  }
  __shared__ int s_ok;
  __shared__ float sx[64 * XDW];
  if (threadIdx.x == 0) s_ok = 1;
  __syncthreads();
  if (!ok) s_ok = 0;
  __syncthreads();
  const bool fast = (s_ok != 0);

  float h[NST];
  size_t sb = (((size_t)b * NCH + c) * DI + d) * 32;
#pragma unroll
  for (int n = 0; n < NST; ++n) h[n] = states[sb + n];
  const float wdt = W_dt[d], bdt = b_dt[d];
  const float Dd = Dp[d];
  const size_t rbase = (size_t)b * LL + c * CLEN;

  float xv = b2f(xs[rbase * DI + d]);
  float zv = b2f(xz[rbase * 4096 + DI + d]);

  if (fast) {
    for (int s = 0; s < CLEN; s += 64) {
      __syncthreads();
      const float* xg = xdbl + (rbase + s) * XDW;
      for (int q = threadIdx.x; q < 64 * XDW; q += 256) sx[q] = xg[q];
      __syncthreads();
#pragma unroll 2
      for (int u = 0; u < 64; ++u) {
        size_t r = rbase + s + u;
        int tn = s + u + 1;
        float nx = 0.f, nz = 0.f;
        if (tn < CLEN) {
          nx = b2f(xs[(rbase + tn) * DI + d]);
          nz = b2f(xz[(rbase + tn) * 4096 + DI + d]);
        }
        float dtr = sx[u * XDW];
        float dt = softplus(fmaf(dtr, wdt, bdt));
        float dx = dt * xv;
        float y = Dd * xv;
        float wv[NST];
        wv[0] = exp2f(dt * A2_0);
#pragma unroll
        for (int n = 1; n < NST; ++n)
          wv[n] = wv[(n - 1) >> 1] * wv[n - 1 - ((n - 1) >> 1)];
        const float4* Bp = (const float4*)&sx[u * XDW + 4];
        const float4* Cp = (const float4*)&sx[u * XDW + 20];
#pragma unroll
        for (int n4 = 0; n4 < 4; ++n4) {
          float4 Bv = Bp[n4];
          float4 Cv = Cp[n4];
          float bb[4] = {Bv.x, Bv.y, Bv.z, Bv.w};
          float cc[4] = {Cv.x, Cv.y, Cv.z, Cv.w};
#pragma unroll
          for (int k = 0; k < 4; ++k) {
            int n = n4 * 4 + k;
            h[n] = fmaf(wv[n], h[n], dx * bb[k]);
            y = fmaf(h[n], cc[k], y);
          }
        }
        xs[r * DI + d] = f2b(y * silu(zv));
        xv = nx; zv = nz;
      }
    }
  } else {
    float A2[NST];
#pragma unroll
    for (int n = 0; n < NST; ++n)
      A2[n] = -__expf(A_log[(size_t)d * NST + n]) * 1.44269504f;
    for (int s = 0; s < CLEN; s += 64) {
      __syncthreads();
      const float* xg = xdbl + (rbase + s) * XDW;
      for (int q = threadIdx.x; q < 64 * XDW; q += 256) sx[q] = xg[q];
      __syncthreads();
#pragma unroll 2
      for (int u = 0; u < 64; ++u) {
        size_t r = rbase + s + u;
        int tn = s + u + 1;
        float nx = 0.f, nz = 0.f;
        if (tn < CLEN) {
          nx = b2f(xs[(rbase + tn) * DI + d]);
          nz = b2f(xz[(rbase + tn) * 4096 + DI + d]);
        }
        float dtr = sx[u * XDW];
        float dt = softplus(fmaf(dtr, wdt, bdt));
        float dx = dt * xv;
        float y = Dd * xv;
        const float4* Bp = (const float4*)&sx[u * XDW + 4];
        const float4* Cp = (const float4*)&sx[u * XDW + 20];
#pragma unroll
        for (int n4 = 0; n4 < 4; ++n4) {
          float4 Bv = Bp[n4];
          float4 Cv = Cp[n4];
          float bb[4] = {Bv.x, Bv.y, Bv.z, Bv.w};
          float cc[4] = {Cv.x, Cv.y, Cv.z, Cv.w};
#pragma unroll
          for (int k = 0; k < 4; ++k) {
            int n = n4 * 4 + k;
            h[n] = fmaf(exp2f(dt * A2[n]), h[n], dx * bb[k]);
            y = fmaf(h[n], cc[k], y);
          }
        }
        xs[r * DI + d] = f2b(y * silu(zv));
        xv = nx; zv = nz;
      }
    }
  }
}

// ---------------------------------------------------------------------------
extern "C" void kernel_launch(void* const* d_in, const int* in_sizes, int n_in,
                              void* d_out, int out_size, void* d_ws, size_t ws_size,
                              hipStream_t stream)
{
  const float* x     = (const float*)d_in[0];
  const float* W_in  = (const float*)d_in[1];
  const float* cw    = (const float*)d_in[2];
  const float* cb    = (const float*)d_in[3];
  const float* W_x   = (const float*)d_in[4];
  const float* W_dt  = (const float*)d_in[5];
  const float* b_dt  = (const float*)d_in[6];
  const float* A_log = (const float*)d_in[7];
  const float* Dp    = (const float*)d_in[8];
  const float* W_out = (const float*)d_in[9];
  float* out = (float*)d_out;

  // ws (proven-safe footprint): xz bf16 [16384,4096] | xs bf16 [16384,2048]
  bf16_t* xz = (bf16_t*)d_ws;
  bf16_t* xs = xz + (size_t)MR * 4096;

  // d_out (64 MiB fp32) as phase-disjoint scratch:
  //   conversions: x_bf [0,32M) | Win_bf [32M,40M) | Wx_bf [40M,40.25M)
  //   scan:        states [0,33.6M) | xdbl [33.6M,36M)  (x_bf/Win_bf dead)
  //   GEMM3 output overwrites everything last.
  bf16_t* x_bf    = (bf16_t*)d_out;
  bf16_t* Win_bf  = x_bf + (size_t)MR * DMOD;
  bf16_t* Wx_bf   = Win_bf + (size_t)4096 * DMOD;
  float*  states  = (float*)d_out;
  float*  xdbl    = states + (size_t)BB * NCH * DI * 32;   // 8.39M floats in
  bf16_t* Wout_bf = xz;   // overlays dead xz after scan pass 3

  // 0) operand conversions
  cvt_bf16<<<(MR*DMOD/4 + 255)/256, 256, 0, stream>>>(x, x_bf, MR*DMOD/4);
  cvt_bf16<<<(4096*DMOD/4 + 255)/256, 256, 0, stream>>>(W_in, Win_bf, 4096*DMOD/4);
  cvt_wx<<<(64*DI)/256, 256, 0, stream>>>(W_x, Wx_bf);
  // 1) xz = x @ W_in^T   (M=16384, N=4096, K=1024) bf16 MFMA
  mgemm_nt<bf16_t><<<dim3(4096/128, MR/128), 256, 0, stream>>>(x_bf, Win_bf, xz, 4096, DMOD);
  // 2) causal depthwise conv + bias + SiLU -> xs (bf16)
  conv_silu<<<(BB*LL*512)/256, 256, 0, stream>>>(xz, cw, cb, xs);
  // 3) x_dbl (padded rows) = xs @ W_x^T (MFMA)
  xdbl_mfma<<<MR/64, 256, 0, stream>>>(xs, Wx_bf, xdbl);
  // 4) chunked selective scan (3 passes) + D*xs + SiLU(z) gate, in place in xs
  scan_pass1<<<BB*NCH*8, 256, 0, stream>>>(xdbl, xs, W_dt, b_dt, A_log, states);
  scan_pass2<<<(BB*DI*NST)/256, 256, 0, stream>>>(states);
  scan_pass3<<<BB*NCH*8, 256, 0, stream>>>(xdbl, xz, xs, states, W_dt, b_dt, A_log, Dp);
  // 5) W_out -> bf16 (dead xz region), then out = gated @ W_out^T
  cvt_bf16<<<(DMOD*DI/4 + 255)/256, 256, 0, stream>>>(W_out, Wout_bf, DMOD*DI/4);
  mgemm_nt<float><<<dim3(DMOD/128, MR/128), 256, 0, stream>>>(xs, Wout_bf, out, DMOD, DI);
}

// Round 3
// 732.882 us; speedup vs baseline: 1.3156x; 1.0324x over previous
//
#include <hip/hip_runtime.h>
#include <math.h>

// Problem constants (fixed by the reference)
#define BB    8
#define LL    2048
#define DMOD  1024
#define DI    2048
#define NST   16
#define MR    (BB*LL)   // 16384 rows
// scan chunking
#define NCH   16
#define CLEN  128       // NCH*CLEN == LL
#define XDW   36        // padded xdbl row: [dt, pad,pad,pad, B0..15, C0..15]

typedef unsigned short bf16_t;
typedef __attribute__((ext_vector_type(8))) __bf16 bf16x8;
typedef __attribute__((ext_vector_type(4))) float  f32x4;

__device__ __forceinline__ float b2f(bf16_t u) {
  return __uint_as_float(((unsigned int)u) << 16);
}
// HW bf16 convert (v_cvt_pk_bf16_f32, RNE) -- bit-identical to manual RNE
// for normal values, 1 VALU op instead of 5.
__device__ __forceinline__ bf16_t f2bn(float f) {
  __bf16 h = (__bf16)f;
  return *(bf16_t*)&h;
}

__device__ __forceinline__ void cstore(float* p, float v)  { *p = v; }
__device__ __forceinline__ void cstore(bf16_t* p, float v) { *p = f2bn(v); }

// async global->LDS, 16B per lane; LDS dest = wave-uniform base + lane*16
__device__ __forceinline__ void gld16(const bf16_t* g, bf16_t* l) {
  __builtin_amdgcn_global_load_lds(
      (const __attribute__((address_space(1))) unsigned int*)g,
      (__attribute__((address_space(3))) unsigned int*)l, 16, 0, 0);
}

// softplus via 2 HW transcendentals (abs err ~1e-7, fine vs 5.5e-4 budget)
__device__ __forceinline__ float softplus(float x) {
  return (x > 20.f) ? x : __logf(1.f + __expf(x));
}
__device__ __forceinline__ float silu(float z) {
  return z * __builtin_amdgcn_rcpf(1.f + __expf(-z));
}

// ---------------------------------------------------------------------------
// fp32 -> bf16 convert (vectorized x4)
// ---------------------------------------------------------------------------
__global__ __launch_bounds__(256) void cvt_bf16(
    const float* __restrict__ in, bf16_t* __restrict__ out, int n4)
{
  int i = blockIdx.x * 256 + threadIdx.x;
  if (i >= n4) return;
  float4 v = ((const float4*)in)[i];
  ushort4 u;
  u.x = f2bn(v.x); u.y = f2bn(v.y); u.z = f2bn(v.z); u.w = f2bn(v.w);
  ((ushort4*)out)[i] = u;
}

// W_x [33,2048] fp32 -> padded bf16 [64,2048] (rows 33..63 zero)
__global__ __launch_bounds__(256) void cvt_wx(
    const float* __restrict__ W_x, bf16_t* __restrict__ Wx_bf)
{
  int i = blockIdx.x * 256 + threadIdx.x;   // 64*2048 = 131072
  int j = i >> 11;
  Wx_bf[i] = (j < 33) ? f2bn(W_x[i]) : (bf16_t)0;
}

// ---------------------------------------------------------------------------
// MFMA GEMM NT: C[M,N] = A[M,K] * B[N,K]^T, bf16 inputs, fp32 acc.
// 128x128 tile, BK=32, 256 thr (4 waves), 4x4 16x16x32 per wave.
// XCD-chunked blockIdx swizzle (T1): blocks resident on one XCD cover a
// contiguous tile range -> A-panels stay L2-local.  Bijective: nwg%8==0.
// ---------------------------------------------------------------------------
template <typename TC>
__global__ __launch_bounds__(256) void mgemm_nt(
    const bf16_t* __restrict__ A, const bf16_t* __restrict__ B,
    TC* __restrict__ C, int N, int K)
{
  __shared__ __align__(16) bf16_t As[128 * 32];
  __shared__ __align__(16) bf16_t Bs[128 * 32];
  const int tid  = threadIdx.x;
  const int wave = tid >> 6;
  const int lane = tid & 63;

  // T1 XCD swizzle (N is a power of two, so nbx is too)
  const int nbx  = N >> 7;
  const int lg   = 31 - __clz(nbx);
  const int nwg  = (int)(gridDim.x * gridDim.y);
  const int flat = (int)(blockIdx.y * gridDim.x + blockIdx.x);
  const int swz  = (flat & 7) * (nwg >> 3) + (flat >> 3);
  const int m0 = (swz >> lg) * 128;
  const int n0 = (swz & (nbx - 1)) * 128;

  const int wm = (wave >> 1) * 64;
  const int wn = (wave & 1) * 64;
  const int fr = lane & 15;
  const int quad = lane >> 4;

  const int srow = wave * 32 + (lane >> 2);
  const int scol = (lane & 3) * 8;
  const bf16_t* Ag0 = A + (size_t)(m0 + srow) * K + scol;
  const bf16_t* Ag1 = Ag0 + (size_t)16 * K;
  const bf16_t* Bg0 = B + (size_t)(n0 + srow) * K + scol;
  const bf16_t* Bg1 = Bg0 + (size_t)16 * K;
  bf16_t* lA0 = As + (wave * 32) * 32;
  bf16_t* lA1 = As + (wave * 32 + 16) * 32;
  bf16_t* lB0 = Bs + (wave * 32) * 32;
  bf16_t* lB1 = Bs + (wave * 32 + 16) * 32;

  f32x4 acc[4][4];
#pragma unroll
  for (int i = 0; i < 4; ++i)
#pragma unroll
    for (int j = 0; j < 4; ++j) acc[i][j] = (f32x4){0.f, 0.f, 0.f, 0.f};

  for (int k0 = 0; k0 < K; k0 += 32) {
    __syncthreads();
    gld16(Ag0 + k0, lA0);
    gld16(Ag1 + k0, lA1);
    gld16(Bg0 + k0, lB0);
    gld16(Bg1 + k0, lB1);
    __syncthreads();

    bf16x8 a[4], b[4];
#pragma unroll
    for (int i = 0; i < 4; ++i)
      a[i] = *(const bf16x8*)&As[(wm + i * 16 + fr) * 32 + quad * 8];
#pragma unroll
    for (int j = 0; j < 4; ++j)
      b[j] = *(const bf16x8*)&Bs[(wn + j * 16 + fr) * 32 + quad * 8];
#pragma unroll
    for (int i = 0; i < 4; ++i)
#pragma unroll
      for (int j = 0; j < 4; ++j)
        acc[i][j] = __builtin_amdgcn_mfma_f32_16x16x32_bf16(a[i], b[j], acc[i][j], 0, 0, 0);
  }

  // D col = lane&15, row = quad*4 + r
#pragma unroll
  for (int i = 0; i < 4; ++i)
#pragma unroll
    for (int j = 0; j < 4; ++j) {
#pragma unroll
      for (int r = 0; r < 4; ++r) {
        int grow = m0 + wm + i * 16 + quad * 4 + r;
        int gcol = n0 + wn + j * 16 + fr;
        cstore(&C[(size_t)grow * N + gcol], acc[i][j][r]);
      }
    }
}

// ---------------------------------------------------------------------------
// x_dbl MFMA GEMM: xdbl[M,36pad] = xs[M,2048] * Wx_bf[64,2048]^T.
// BM=64, BK=64, 4 waves; wave w owns row-tile w, 3 col-tiles. grid = MR/64.
// Output row layout: dt at col 0, B at 4..19, C at 20..35.
// ---------------------------------------------------------------------------
__global__ __launch_bounds__(256) void xdbl_mfma(
    const bf16_t* __restrict__ xs, const bf16_t* __restrict__ Wx_bf,
    float* __restrict__ xdbl)
{
  __shared__ __align__(16) bf16_t As[2 * 64 * 32];
  __shared__ __align__(16) bf16_t Bs[2 * 64 * 32];
  const int tid  = threadIdx.x;
  const int wave = tid >> 6;
  const int lane = tid & 63;
  const int m0 = blockIdx.x * 64;
  const int fr = lane & 15;
  const int quad = lane >> 4;

  const int srow = wave * 16 + (lane >> 2);
  const int scol = (lane & 3) * 8;
  const bf16_t* Ag = xs + (size_t)(m0 + srow) * DI + scol;
  const bf16_t* Bg = Wx_bf + (size_t)srow * DI + scol;
  bf16_t* lA = As + wave * 512;
  bf16_t* lB = Bs + wave * 512;

  f32x4 acc[3];
#pragma unroll
  for (int jt = 0; jt < 3; ++jt) acc[jt] = (f32x4){0.f, 0.f, 0.f, 0.f};

  for (int k0 = 0; k0 < DI; k0 += 64) {
    __syncthreads();
#pragma unroll
    for (int kk = 0; kk < 2; ++kk) {
      gld16(Ag + k0 + kk * 32, lA + kk * 2048);
      gld16(Bg + k0 + kk * 32, lB + kk * 2048);
    }
    __syncthreads();

#pragma unroll
    for (int kk = 0; kk < 2; ++kk) {
      bf16x8 a = *(const bf16x8*)&As[kk * 2048 + (wave * 16 + fr) * 32 + quad * 8];
#pragma unroll
      for (int jt = 0; jt < 3; ++jt) {
        bf16x8 b = *(const bf16x8*)&Bs[kk * 2048 + (jt * 16 + fr) * 32 + quad * 8];
        acc[jt] = __builtin_amdgcn_mfma_f32_16x16x32_bf16(a, b, acc[jt], 0, 0, 0);
      }
    }
  }

#pragma unroll
  for (int jt = 0; jt < 3; ++jt) {
#pragma unroll
    for (int r = 0; r < 4; ++r) {
      int grow = m0 + wave * 16 + quad * 4 + r;
      int j = jt * 16 + fr;
      if (j < 33) {
        int col = (j == 0) ? 0 : (j + 3);
        xdbl[(size_t)grow * XDW + col] = acc[jt][r];
      }
    }
  }
}

// ---------------------------------------------------------------------------
// Causal depthwise conv1d (k=4) + bias + SiLU.  bf16 xz -> bf16 xs.
// ---------------------------------------------------------------------------
__global__ __launch_bounds__(256) void conv_silu(
    const bf16_t* __restrict__ xz, const float* __restrict__ cw,
    const float* __restrict__ cb, bf16_t* __restrict__ xs)
{
  int idx = blockIdx.x * 256 + threadIdx.x;
  int d4 = idx & 511;
  int l  = (idx >> 9) & 2047;
  int b  = idx >> 20;
  int d  = d4 * 4;

  float wch[4][4];
#pragma unroll
  for (int c = 0; c < 4; ++c)
#pragma unroll
    for (int k = 0; k < 4; ++k) wch[c][k] = cw[(d + c) * 4 + k];

  float acc0 = cb[d+0], acc1 = cb[d+1], acc2 = cb[d+2], acc3 = cb[d+3];
  size_t rowbase = ((size_t)b * LL + l) * 4096 + d;
#pragma unroll
  for (int k = 0; k < 4; ++k) {
    if (l - 3 + k >= 0) {
      ushort4 u = *(const ushort4*)(xz + rowbase - (size_t)(3 - k) * 4096);
      acc0 += b2f(u.x) * wch[0][k];
      acc1 += b2f(u.y) * wch[1][k];
      acc2 += b2f(u.z) * wch[2][k];
      acc3 += b2f(u.w) * wch[3][k];
    }
  }
  ushort4 o;
  o.x = f2bn(silu(acc0)); o.y = f2bn(silu(acc1));
  o.z = f2bn(silu(acc2)); o.w = f2bn(silu(acc3));
  *(ushort4*)(xs + ((size_t)b * LL + l) * (size_t)DI + d) = o;
}

// ---------------------------------------------------------------------------
// Scan pass 1: per (b, chunk) scan from h=0; ONE channel per thread.
// grid: 1024 = b(8) x chunk(16) x dgroup(8); thread covers d = dg*256+tid.
//
// FAST PATH: the reference fixes A[d,n] = -(n+1), so
//   exp2(dt*A2[n]) == w^(n+1) with w = exp2(dt*A2[0]).
// One v_exp + 15 muls per timestep instead of 16 v_exp.  Verified per
// thread against A_log at init; block-uniform fallback to the exact
// per-n path otherwise (branch must be block-uniform: both paths
// contain __syncthreads).
// states: [b][c][d][32] fp32 (0..15 P, 16..31 h_end).
// ---------------------------------------------------------------------------
__global__ __launch_bounds__(256) void scan_pass1(
    const float* __restrict__ xdbl, const bf16_t* __restrict__ xs,
    const float* __restrict__ W_dt, const float* __restrict__ b_dt,
    const float* __restrict__ A_log, float* __restrict__ states)
{
  const int bid = blockIdx.x;
  const int dg = bid & 7, c = (bid >> 3) & 15, b = bid >> 7;
  const int d = dg * 256 + threadIdx.x;

  const float A2_0 = -__expf(A_log[(size_t)d * NST]) * 1.44269504f;
  bool ok = true;
#pragma unroll
  for (int n = 1; n < NST; ++n) {
    float a = -__expf(A_log[(size_t)d * NST + n]) * 1.44269504f;
    ok = ok && (fabsf(a - (float)(n + 1) * A2_0) <= 1e-3f * (float)(n + 1));
  }
  __shared__ int s_ok;
  __shared__ float sx[64 * XDW];
  if (threadIdx.x == 0) s_ok = 1;
  __syncthreads();
  if (!ok) s_ok = 0;           // benign race: only 0 is written
  __syncthreads();
  const bool fast = (s_ok != 0);

  float h[NST];
#pragma unroll
  for (int n = 0; n < NST; ++n) h[n] = 0.f;
  const float wdt = W_dt[d], bdt = b_dt[d];
  float dts = 0.f;
  const size_t rbase = (size_t)b * LL + c * CLEN;
  float xv = b2f(xs[rbase * DI + d]);

  if (fast) {
    for (int s = 0; s < CLEN; s += 64) {
      __syncthreads();
      const float* xg = xdbl + (rbase + s) * XDW;
      for (int q = threadIdx.x; q < 64 * XDW; q += 256) sx[q] = xg[q];
      __syncthreads();
#pragma unroll 2
      for (int u = 0; u < 64; ++u) {
        int tn = s + u + 1;
        float nx = 0.f;
        if (tn < CLEN) nx = b2f(xs[(rbase + tn) * DI + d]);
        float dtr = sx[u * XDW];
        float dt = softplus(fmaf(dtr, wdt, bdt));
        dts += dt;
        float dx = dt * xv;
        float wv[NST];
        wv[0] = exp2f(dt * A2_0);
#pragma unroll
        for (int n = 1; n < NST; ++n)
          wv[n] = wv[(n - 1) >> 1] * wv[n - 1 - ((n - 1) >> 1)];  // w^(n+1), depth 4
        const float4* Bp = (const float4*)&sx[u * XDW + 4];
#pragma unroll
        for (int n4 = 0; n4 < 4; ++n4) {
          float4 Bv = Bp[n4];
          float bb[4] = {Bv.x, Bv.y, Bv.z, Bv.w};
#pragma unroll
          for (int k = 0; k < 4; ++k) {
            int n = n4 * 4 + k;
            h[n] = fmaf(wv[n], h[n], dx * bb[k]);
          }
        }
        xv = nx;
      }
    }
    size_t sb = (((size_t)b * NCH + c) * DI + d) * 32;
    float Wv[NST];
    Wv[0] = exp2f(dts * A2_0);
#pragma unroll
    for (int n = 1; n < NST; ++n)
      Wv[n] = Wv[(n - 1) >> 1] * Wv[n - 1 - ((n - 1) >> 1)];
#pragma unroll
    for (int n = 0; n < NST; ++n) {
      states[sb + n]      = Wv[n];
      states[sb + 16 + n] = h[n];
    }
  } else {
    float A2[NST];
#pragma unroll
    for (int n = 0; n < NST; ++n)
      A2[n] = -__expf(A_log[(size_t)d * NST + n]) * 1.44269504f;
    for (int s = 0; s < CLEN; s += 64) {
      __syncthreads();
      const float* xg = xdbl + (rbase + s) * XDW;
      for (int q = threadIdx.x; q < 64 * XDW; q += 256) sx[q] = xg[q];
      __syncthreads();
#pragma unroll 2
      for (int u = 0; u < 64; ++u) {
        int tn = s + u + 1;
        float nx = 0.f;
        if (tn < CLEN) nx = b2f(xs[(rbase + tn) * DI + d]);
        float dtr = sx[u * XDW];
        float dt = softplus(fmaf(dtr, wdt, bdt));
        dts += dt;
        float dx = dt * xv;
        const float4* Bp = (const float4*)&sx[u * XDW + 4];
#pragma unroll
        for (int n4 = 0; n4 < 4; ++n4) {
          float4 Bv = Bp[n4];
          float bb[4] = {Bv.x, Bv.y, Bv.z, Bv.w};
#pragma unroll
          for (int k = 0; k < 4; ++k) {
            int n = n4 * 4 + k;
            h[n] = fmaf(exp2f(dt * A2[n]), h[n], dx * bb[k]);
          }
        }
        xv = nx;
      }
    }
    size_t sb = (((size_t)b * NCH + c) * DI + d) * 32;
#pragma unroll
    for (int n = 0; n < NST; ++n) {
      states[sb + n]      = exp2f(dts * A2[n]);
      states[sb + 16 + n] = h[n];
    }
  }
}

// ---------------------------------------------------------------------------
// Scan pass 2: compose chunk states sequentially; h_init -> P slot (in place).
// ---------------------------------------------------------------------------
__global__ __launch_bounds__(256) void scan_pass2(float* __restrict__ states)
{
  int t = blockIdx.x * 256 + threadIdx.x;    // 8*2048*16 = 262144
  int n = t & 15, d = (t >> 4) & 2047, b = t >> 15;
  float h = 0.f;
  for (int c = 0; c < NCH; ++c) {
    size_t sb = (((size_t)b * NCH + c) * DI + d) * 32;
    float P  = states[sb + n];
    float h0 = states[sb + 16 + n];
    states[sb + n] = h;          // h_init entering chunk c
    h = fmaf(P, h, h0);
  }
}

// ---------------------------------------------------------------------------
// Scan pass 3: re-scan from h_init; y = C.h + D*x; gate SiLU(z); bf16 in place.
// ONE channel per thread; same FAST-path power-chain trick as pass 1.
// ---------------------------------------------------------------------------
__global__ __launch_bounds__(256) void scan_pass3(
    const float* __restrict__ xdbl, const bf16_t* __restrict__ xz,
    bf16_t* __restrict__ xs, const float* __restrict__ states,
    const float* __restrict__ W_dt, const float* __restrict__ b_dt,
    const float* __restrict__ A_log, const float* __restrict__ Dp)
{
  const int bid = blockIdx.x;
  const int dg = bid & 7, c = (bid >> 3) & 15, b = bid >> 7;
  const int d = dg * 256 + threadIdx.x;

  const float A2_0 = -__expf(A_log[(size_t)d * NST]) * 1.44269504f;
  bool ok = true;
#pragma unroll
  for (int n = 1; n < NST; ++n) {
    float a = -__expf(A_log[(size_t)d * NST + n]) * 1.44269504f;
    ok = ok && (fabsf(a - (float)(n + 1) * A2_0) <= 1e-3f * (float)(n + 1));
  }
  __shared__ int s_ok;
  __shared__ float sx[64 * XDW];
  if (threadIdx.x == 0) s_ok = 1;
  __syncthreads();
  if (!ok) s_ok = 0;
  __syncthreads();
  const bool fast = (s_ok != 0);

  float h[NST];
  size_t sb = (((size_t)b * NCH + c) * DI + d) * 32;
#pragma unroll
  for (int n = 0; n < NST; ++n) h[n] = states[sb + n];
  const float wdt = W_dt[d], bdt = b_dt[d];
  const float Dd = Dp[d];
  const size_t rbase = (size_t)b * LL + c * CLEN;

  float xv = b2f(xs[rbase * DI + d]);
  float zv = b2f(xz[rbase * 4096 + DI + d]);

  if (fast) {
    for (int s = 0; s < CLEN; s += 64) {
      __syncthreads();
      const float* xg = xdbl + (rbase + s) * XDW;
      for (int q = threadIdx.x; q < 64 * XDW; q += 256) sx[q] = xg[q];
      __syncthreads();
#pragma unroll 2
      for (int u = 0; u < 64; ++u) {
        size_t r = rbase + s + u;
        int tn = s + u + 1;
        float nx = 0.f, nz = 0.f;
        if (tn < CLEN) {
          nx = b2f(xs[(rbase + tn) * DI + d]);
          nz = b2f(xz[(rbase + tn) * 4096 + DI + d]);
        }
        float dtr = sx[u * XDW];
        float dt = softplus(fmaf(dtr, wdt, bdt));
        float dx = dt * xv;
        float y = Dd * xv;
        float wv[NST];
        wv[0] = exp2f(dt * A2_0);
#pragma unroll
        for (int n = 1; n < NST; ++n)
          wv[n] = wv[(n - 1) >> 1] * wv[n - 1 - ((n - 1) >> 1)];
        const float4* Bp = (const float4*)&sx[u * XDW + 4];
        const float4* Cp = (const float4*)&sx[u * XDW + 20];
#pragma unroll
        for (int n4 = 0; n4 < 4; ++n4) {
          float4 Bv = Bp[n4];
          float4 Cv = Cp[n4];
          float bb[4] = {Bv.x, Bv.y, Bv.z, Bv.w};
          float cc[4] = {Cv.x, Cv.y, Cv.z, Cv.w};
#pragma unroll
          for (int k = 0; k < 4; ++k) {
            int n = n4 * 4 + k;
            h[n] = fmaf(wv[n], h[n], dx * bb[k]);
            y = fmaf(h[n], cc[k], y);
          }
        }
        xs[r * DI + d] = f2bn(y * silu(zv));
        xv = nx; zv = nz;
      }
    }
  } else {
    float A2[NST];
#pragma unroll
    for (int n = 0; n < NST; ++n)
      A2[n] = -__expf(A_log[(size_t)d * NST + n]) * 1.44269504f;
    for (int s = 0; s < CLEN; s += 64) {
      __syncthreads();
      const float* xg = xdbl + (rbase + s) * XDW;
      for (int q = threadIdx.x; q < 64 * XDW; q += 256) sx[q] = xg[q];
      __syncthreads();
#pragma unroll 2
      for (int u = 0; u < 64; ++u) {
        size_t r = rbase + s + u;
        int tn = s + u + 1;
        float nx = 0.f, nz = 0.f;
        if (tn < CLEN) {
          nx = b2f(xs[(rbase + tn) * DI + d]);
          nz = b2f(xz[(rbase + tn) * 4096 + DI + d]);
        }
        float dtr = sx[u * XDW];
        float dt = softplus(fmaf(dtr, wdt, bdt));
        float dx = dt * xv;
        float y = Dd * xv;
        const float4* Bp = (const float4*)&sx[u * XDW + 4];
        const float4* Cp = (const float4*)&sx[u * XDW + 20];
#pragma unroll
        for (int n4 = 0; n4 < 4; ++n4) {
          float4 Bv = Bp[n4];
          float4 Cv = Cp[n4];
          float bb[4] = {Bv.x, Bv.y, Bv.z, Bv.w};
          float cc[4] = {Cv.x, Cv.y, Cv.z, Cv.w};
#pragma unroll
          for (int k = 0; k < 4; ++k) {
            int n = n4 * 4 + k;
            h[n] = fmaf(exp2f(dt * A2[n]), h[n], dx * bb[k]);
            y = fmaf(h[n], cc[k], y);
          }
        }
        xs[r * DI + d] = f2bn(y * silu(zv));
        xv = nx; zv = nz;
      }
    }
  }
}

// ---------------------------------------------------------------------------
extern "C" void kernel_launch(void* const* d_in, const int* in_sizes, int n_in,
                              void* d_out, int out_size, void* d_ws, size_t ws_size,
                              hipStream_t stream)
{
  const float* x     = (const float*)d_in[0];
  const float* W_in  = (const float*)d_in[1];
  const float* cw    = (const float*)d_in[2];
  const float* cb    = (const float*)d_in[3];
  const float* W_x   = (const float*)d_in[4];
  const float* W_dt  = (const float*)d_in[5];
  const float* b_dt  = (const float*)d_in[6];
  const float* A_log = (const float*)d_in[7];
  const float* Dp    = (const float*)d_in[8];
  const float* W_out = (const float*)d_in[9];
  float* out = (float*)d_out;

  // ws (proven-safe footprint): xz bf16 [16384,4096] | xs bf16 [16384,2048]
  bf16_t* xz = (bf16_t*)d_ws;
  bf16_t* xs = xz + (size_t)MR * 4096;

  // d_out (64 MiB fp32) as phase-disjoint scratch:
  //   conversions: x_bf [0,32M) | Win_bf [32M,40M) | Wx_bf [40M,40.25M)
  //   scan:        states [0,33.6M) | xdbl [33.6M,36M)  (x_bf/Win_bf dead)
  //   GEMM3 output overwrites everything last.
  bf16_t* x_bf    = (bf16_t*)d_out;
  bf16_t* Win_bf  = x_bf + (size_t)MR * DMOD;
  bf16_t* Wx_bf   = Win_bf + (size_t)4096 * DMOD;
  float*  states  = (float*)d_out;
  float*  xdbl    = states + (size_t)BB * NCH * DI * 32;   // 8.39M floats in
  bf16_t* Wout_bf = xz;   // overlays dead xz after scan pass 3

  // 0) operand conversions
  cvt_bf16<<<(MR*DMOD/4 + 255)/256, 256, 0, stream>>>(x, x_bf, MR*DMOD/4);
  cvt_bf16<<<(4096*DMOD/4 + 255)/256, 256, 0, stream>>>(W_in, Win_bf, 4096*DMOD/4);
  cvt_wx<<<(64*DI)/256, 256, 0, stream>>>(W_x, Wx_bf);
  // 1) xz = x @ W_in^T   (M=16384, N=4096, K=1024) bf16 MFMA
  mgemm_nt<bf16_t><<<dim3(4096/128, MR/128), 256, 0, stream>>>(x_bf, Win_bf, xz, 4096, DMOD);
  // 2) causal depthwise conv + bias + SiLU -> xs (bf16)
  conv_silu<<<(BB*LL*512)/256, 256, 0, stream>>>(xz, cw, cb, xs);
  // 3) x_dbl (padded rows) = xs @ W_x^T (MFMA)
  xdbl_mfma<<<MR/64, 256, 0, stream>>>(xs, Wx_bf, xdbl);
  // 4) chunked selective scan (3 passes) + D*xs + SiLU(z) gate, in place in xs
  scan_pass1<<<BB*NCH*8, 256, 0, stream>>>(xdbl, xs, W_dt, b_dt, A_log, states);
  scan_pass2<<<(BB*DI*NST)/256, 256, 0, stream>>>(states);
  scan_pass3<<<BB*NCH*8, 256, 0, stream>>>(xdbl, xz, xs, states, W_dt, b_dt, A_log, Dp);
  // 5) W_out -> bf16 (dead xz region), then out = gated @ W_out^T
  cvt_bf16<<<(DMOD*DI/4 + 255)/256, 256, 0, stream>>>(W_out, Wout_bf, DMOD*DI/4);
  mgemm_nt<float><<<dim3(DMOD/128, MR/128), 256, 0, stream>>>(xs, Wout_bf, out, DMOD, DI);
}

// Round 4
// 720.108 us; speedup vs baseline: 1.3389x; 1.0177x over previous
//
#include <hip/hip_runtime.h>
#include <math.h>

// Problem constants (fixed by the reference)
#define BB    8
#define LL    2048
#define DMOD  1024
#define DI    2048
#define NST   16
#define MR    (BB*LL)   // 16384 rows
// scan chunking
#define NCH   16
#define CLEN  128       // NCH*CLEN == LL
#define XDW   36        // padded xdbl row: [dt, pad,pad,pad, B0..15, C0..15]

typedef unsigned short bf16_t;
typedef __attribute__((ext_vector_type(8))) __bf16 bf16x8;
typedef __attribute__((ext_vector_type(4))) float  f32x4;

__device__ __forceinline__ float b2f(bf16_t u) {
  return __uint_as_float(((unsigned int)u) << 16);
}
// HW bf16 convert (RNE) -- 1 VALU op
__device__ __forceinline__ bf16_t f2bn(float f) {
  __bf16 h = (__bf16)f;
  return *(bf16_t*)&h;
}

__device__ __forceinline__ void cstore(float* p, float v)  { *p = v; }
__device__ __forceinline__ void cstore(bf16_t* p, float v) { *p = f2bn(v); }

// async global->LDS, 16B per lane; LDS dest = wave-uniform base + lane*16
__device__ __forceinline__ void gld16(const bf16_t* g, bf16_t* l) {
  __builtin_amdgcn_global_load_lds(
      (const __attribute__((address_space(1))) unsigned int*)g,
      (__attribute__((address_space(3))) unsigned int*)l, 16, 0, 0);
}

// softplus via 2 HW transcendentals (abs err ~1e-7, fine vs 5.5e-4 budget)
__device__ __forceinline__ float softplus(float x) {
  return (x > 20.f) ? x : __logf(1.f + __expf(x));
}
__device__ __forceinline__ float silu(float z) {
  return z * __builtin_amdgcn_rcpf(1.f + __expf(-z));
}

// ---------------------------------------------------------------------------
// fp32 -> bf16 convert (vectorized x4)
// ---------------------------------------------------------------------------
__global__ __launch_bounds__(256) void cvt_bf16(
    const float* __restrict__ in, bf16_t* __restrict__ out, int n4)
{
  int i = blockIdx.x * 256 + threadIdx.x;
  if (i >= n4) return;
  float4 v = ((const float4*)in)[i];
  ushort4 u;
  u.x = f2bn(v.x); u.y = f2bn(v.y); u.z = f2bn(v.z); u.w = f2bn(v.w);
  ((ushort4*)out)[i] = u;
}

// W_x [33,2048] fp32 -> padded bf16 [64,2048] (rows 33..63 zero)
__global__ __launch_bounds__(256) void cvt_wx(
    const float* __restrict__ W_x, bf16_t* __restrict__ Wx_bf)
{
  int i = blockIdx.x * 256 + threadIdx.x;   // 64*2048 = 131072
  int j = i >> 11;
  Wx_bf[i] = (j < 33) ? f2bn(W_x[i]) : (bf16_t)0;
}

// ---------------------------------------------------------------------------
// Big-tile MFMA GEMM NT: C[M,N] = A[M,K] * B[N,K]^T, bf16 in, fp32 acc.
// 256x256 tile, BK=32, 512 thr (8 waves: 2M x 4N, 128x64 out each).
// 3-buffer LDS pipeline (T3/T4): compute ktile t from buf t%3 while
// prefetching ktile t+2 into buf (t+2)%3.  ONE counted vmcnt(4) + ONE raw
// s_barrier per K-tile -- prefetch loads stay in flight across barriers.
// Race-free proof: buf (t+2)%3 differs from both live bufs t%3,(t+1)%3;
// ds_reads of a buf complete (lgkmcnt before MFMA) before the barrier that
// precedes its re-staging.
// LDS chunk-XOR swizzle, both-sides (rule #21): global source chunk is
// pre-swizzled (gld writes linearly) and ds_read applies the same XOR.
// chunk ^= (row>>1)&3 -> 8-way bank conflict becomes free 2-way.
// ---------------------------------------------------------------------------
template <typename TC>
__global__ __launch_bounds__(512) void mgemm_big(
    const bf16_t* __restrict__ A, const bf16_t* __restrict__ B,
    TC* __restrict__ C, int N, int K)
{
  __shared__ __align__(16) bf16_t As[3][256 * 32];   // 3 x 16 KB
  __shared__ __align__(16) bf16_t Bs[3][256 * 32];   // 3 x 16 KB
  const int tid  = threadIdx.x;
  const int wave = tid >> 6;
  const int lane = tid & 63;
  const int m0 = blockIdx.y * 256;
  const int n0 = blockIdx.x * 256;
  const int fr = lane & 15;
  const int quad = lane >> 4;
  const int wm = (wave >> 2) * 128;   // 2 wave-rows
  const int wn = (wave & 3) * 64;     // 4 wave-cols

  // staging: one call = 512 thr x 16B = 8 KB = 128 rows x 64B; 2 calls/ktile
  const int srow = tid >> 2;                       // row within call
  const int schk = tid & 3;                        // 16B chunk within row
  const int ssw  = schk ^ ((srow >> 1) & 3);       // pre-swizzled source chunk
  const bf16_t* Ag = A + (size_t)(m0 + srow) * K + ssw * 8;
  const bf16_t* Bg = B + (size_t)(n0 + srow) * K + ssw * 8;
  const size_t r128 = (size_t)128 * K;             // rows 128..255 (call 1)

  // swizzled ds_read offsets (elements); frag: row*32 + chunk*8
  int aoff[8], boff[4];
#pragma unroll
  for (int i = 0; i < 8; ++i) {
    int row = wm + i * 16 + fr;
    aoff[i] = row * 32 + ((quad ^ ((row >> 1) & 3)) * 8);
  }
#pragma unroll
  for (int j = 0; j < 4; ++j) {
    int row = wn + j * 16 + fr;
    boff[j] = row * 32 + ((quad ^ ((row >> 1) & 3)) * 8);
  }

  f32x4 acc[8][4];
#pragma unroll
  for (int i = 0; i < 8; ++i)
#pragma unroll
    for (int j = 0; j < 4; ++j) acc[i][j] = (f32x4){0.f, 0.f, 0.f, 0.f};

  const int nkt = K >> 5;
  // prologue: ktile0 -> buf0, ktile1 -> buf1 (issue order matters for vmcnt)
  gld16(Ag,            &As[0][wave * 512]);
  gld16(Ag + r128,     &As[0][4096 + wave * 512]);
  gld16(Bg,            &Bs[0][wave * 512]);
  gld16(Bg + r128,     &Bs[0][4096 + wave * 512]);
  gld16(Ag + 32,       &As[1][wave * 512]);
  gld16(Ag + r128 + 32,&As[1][4096 + wave * 512]);
  gld16(Bg + 32,       &Bs[1][wave * 512]);
  gld16(Bg + r128 + 32,&Bs[1][4096 + wave * 512]);
  asm volatile("s_waitcnt vmcnt(4)\n\ts_barrier" ::: "memory");  // ktile0 ready

  for (int t = 0; t < nkt; ++t) {
    const int p = t % 3;
    if (t + 2 < nkt) {                    // prefetch ktile t+2 -> buf (t+2)%3
      const int p2 = (t + 2) % 3;
      const size_t ko = (size_t)(t + 2) * 32;
      gld16(Ag + ko,        &As[p2][wave * 512]);
      gld16(Ag + r128 + ko, &As[p2][4096 + wave * 512]);
      gld16(Bg + ko,        &Bs[p2][wave * 512]);
      gld16(Bg + r128 + ko, &Bs[p2][4096 + wave * 512]);
    }
    const bf16_t* Ab = &As[p][0];
    const bf16_t* Bb = &Bs[p][0];
    bf16x8 a[8], b[4];
#pragma unroll
    for (int i = 0; i < 8; ++i) a[i] = *(const bf16x8*)&Ab[aoff[i]];
#pragma unroll
    for (int j = 0; j < 4; ++j) b[j] = *(const bf16x8*)&Bb[boff[j]];
    __builtin_amdgcn_s_setprio(1);
#pragma unroll
    for (int i = 0; i < 8; ++i)
#pragma unroll
      for (int j = 0; j < 4; ++j)
        acc[i][j] = __builtin_amdgcn_mfma_f32_16x16x32_bf16(a[i], b[j], acc[i][j], 0, 0, 0);
    __builtin_amdgcn_s_setprio(0);
    if (t + 2 < nkt) {
      // newest 4 loads (ktile t+2) may stay in flight; ktile t+1 is landed
      asm volatile("s_waitcnt vmcnt(4)\n\ts_barrier" ::: "memory");
    } else if (t + 1 < nkt) {
      asm volatile("s_waitcnt vmcnt(0)\n\ts_barrier" ::: "memory");
    }
  }

  // D col = lane&15, row = quad*4 + r (same mapping as verified 128^2 kernel)
#pragma unroll
  for (int i = 0; i < 8; ++i)
#pragma unroll
    for (int j = 0; j < 4; ++j) {
#pragma unroll
      for (int r = 0; r < 4; ++r) {
        int grow = m0 + wm + i * 16 + quad * 4 + r;
        int gcol = n0 + wn + j * 16 + fr;
        cstore(&C[(size_t)grow * N + gcol], acc[i][j][r]);
      }
    }
}

// ---------------------------------------------------------------------------
// x_dbl MFMA GEMM: xdbl[M,36pad] = xs[M,2048] * Wx_bf[64,2048]^T.
// BM=64, BK=64, 4 waves; wave w owns row-tile w, 3 col-tiles. grid = MR/64.
// Output row layout: dt at col 0, B at 4..19, C at 20..35.
// ---------------------------------------------------------------------------
__global__ __launch_bounds__(256) void xdbl_mfma(
    const bf16_t* __restrict__ xs, const bf16_t* __restrict__ Wx_bf,
    float* __restrict__ xdbl)
{
  __shared__ __align__(16) bf16_t As[2 * 64 * 32];
  __shared__ __align__(16) bf16_t Bs[2 * 64 * 32];
  const int tid  = threadIdx.x;
  const int wave = tid >> 6;
  const int lane = tid & 63;
  const int m0 = blockIdx.x * 64;
  const int fr = lane & 15;
  const int quad = lane >> 4;

  const int srow = wave * 16 + (lane >> 2);
  const int scol = (lane & 3) * 8;
  const bf16_t* Ag = xs + (size_t)(m0 + srow) * DI + scol;
  const bf16_t* Bg = Wx_bf + (size_t)srow * DI + scol;
  bf16_t* lA = As + wave * 512;
  bf16_t* lB = Bs + wave * 512;

  f32x4 acc[3];
#pragma unroll
  for (int jt = 0; jt < 3; ++jt) acc[jt] = (f32x4){0.f, 0.f, 0.f, 0.f};

  for (int k0 = 0; k0 < DI; k0 += 64) {
    __syncthreads();
#pragma unroll
    for (int kk = 0; kk < 2; ++kk) {
      gld16(Ag + k0 + kk * 32, lA + kk * 2048);
      gld16(Bg + k0 + kk * 32, lB + kk * 2048);
    }
    __syncthreads();

#pragma unroll
    for (int kk = 0; kk < 2; ++kk) {
      bf16x8 a = *(const bf16x8*)&As[kk * 2048 + (wave * 16 + fr) * 32 + quad * 8];
#pragma unroll
      for (int jt = 0; jt < 3; ++jt) {
        bf16x8 b = *(const bf16x8*)&Bs[kk * 2048 + (jt * 16 + fr) * 32 + quad * 8];
        acc[jt] = __builtin_amdgcn_mfma_f32_16x16x32_bf16(a, b, acc[jt], 0, 0, 0);
      }
    }
  }

#pragma unroll
  for (int jt = 0; jt < 3; ++jt) {
#pragma unroll
    for (int r = 0; r < 4; ++r) {
      int grow = m0 + wave * 16 + quad * 4 + r;
      int j = jt * 16 + fr;
      if (j < 33) {
        int col = (j == 0) ? 0 : (j + 3);
        xdbl[(size_t)grow * XDW + col] = acc[jt][r];
      }
    }
  }
}

// ---------------------------------------------------------------------------
// Causal depthwise conv1d (k=4) + bias + SiLU.  bf16 xz -> bf16 xs.
// ---------------------------------------------------------------------------
__global__ __launch_bounds__(256) void conv_silu(
    const bf16_t* __restrict__ xz, const float* __restrict__ cw,
    const float* __restrict__ cb, bf16_t* __restrict__ xs)
{
  int idx = blockIdx.x * 256 + threadIdx.x;
  int d4 = idx & 511;
  int l  = (idx >> 9) & 2047;
  int b  = idx >> 20;
  int d  = d4 * 4;

  float wch[4][4];
#pragma unroll
  for (int c = 0; c < 4; ++c)
#pragma unroll
    for (int k = 0; k < 4; ++k) wch[c][k] = cw[(d + c) * 4 + k];

  float acc0 = cb[d+0], acc1 = cb[d+1], acc2 = cb[d+2], acc3 = cb[d+3];
  size_t rowbase = ((size_t)b * LL + l) * 4096 + d;
#pragma unroll
  for (int k = 0; k < 4; ++k) {
    if (l - 3 + k >= 0) {
      ushort4 u = *(const ushort4*)(xz + rowbase - (size_t)(3 - k) * 4096);
      acc0 += b2f(u.x) * wch[0][k];
      acc1 += b2f(u.y) * wch[1][k];
      acc2 += b2f(u.z) * wch[2][k];
      acc3 += b2f(u.w) * wch[3][k];
    }
  }
  ushort4 o;
  o.x = f2bn(silu(acc0)); o.y = f2bn(silu(acc1));
  o.z = f2bn(silu(acc2)); o.w = f2bn(silu(acc3));
  *(ushort4*)(xs + ((size_t)b * LL + l) * (size_t)DI + d) = o;
}

// ---------------------------------------------------------------------------
// Scan pass 1: per (b, chunk) scan from h=0; ONE channel per thread.
// grid: 1024 = b(8) x chunk(16) x dgroup(8); thread covers d = dg*256+tid.
// FAST PATH: A[d,n] = -(n+1) => exp2(dt*A2[n]) = w^(n+1), w = exp2(dt*A2_0).
// Verified per thread vs A_log; block-uniform fallback otherwise.
// states: [b][c][d][32] fp32 (0..15 P, 16..31 h_end).
// ---------------------------------------------------------------------------
__global__ __launch_bounds__(256) void scan_pass1(
    const float* __restrict__ xdbl, const bf16_t* __restrict__ xs,
    const float* __restrict__ W_dt, const float* __restrict__ b_dt,
    const float* __restrict__ A_log, float* __restrict__ states)
{
  const int bid = blockIdx.x;
  const int dg = bid & 7, c = (bid >> 3) & 15, b = bid >> 7;
  const int d = dg * 256 + threadIdx.x;

  const float A2_0 = -__expf(A_log[(size_t)d * NST]) * 1.44269504f;
  bool ok = true;
#pragma unroll
  for (int n = 1; n < NST; ++n) {
    float a = -__expf(A_log[(size_t)d * NST + n]) * 1.44269504f;
    ok = ok && (fabsf(a - (float)(n + 1) * A2_0) <= 1e-3f * (float)(n + 1));
  }
  __shared__ int s_ok;
  __shared__ float sx[64 * XDW];
  if (threadIdx.x == 0) s_ok = 1;
  __syncthreads();
  if (!ok) s_ok = 0;           // benign race: only 0 is written
  __syncthreads();
  const bool fast = (s_ok != 0);

  float h[NST];
#pragma unroll
  for (int n = 0; n < NST; ++n) h[n] = 0.f;
  const float wdt = W_dt[d], bdt = b_dt[d];
  float dts = 0.f;
  const size_t rbase = (size_t)b * LL + c * CLEN;
  float xv = b2f(xs[rbase * DI + d]);

  if (fast) {
    for (int s = 0; s < CLEN; s += 64) {
      __syncthreads();
      const float* xg = xdbl + (rbase + s) * XDW;
      for (int q = threadIdx.x; q < 64 * XDW; q += 256) sx[q] = xg[q];
      __syncthreads();
#pragma unroll 2
      for (int u = 0; u < 64; ++u) {
        int tn = s + u + 1;
        float nx = 0.f;
        if (tn < CLEN) nx = b2f(xs[(rbase + tn) * DI + d]);
        float dtr = sx[u * XDW];
        float dt = softplus(fmaf(dtr, wdt, bdt));
        dts += dt;
        float dx = dt * xv;
        float wv[NST];
        wv[0] = exp2f(dt * A2_0);
#pragma unroll
        for (int n = 1; n < NST; ++n)
          wv[n] = wv[(n - 1) >> 1] * wv[n - 1 - ((n - 1) >> 1)];  // w^(n+1), depth 4
        const float4* Bp = (const float4*)&sx[u * XDW + 4];
#pragma unroll
        for (int n4 = 0; n4 < 4; ++n4) {
          float4 Bv = Bp[n4];
          float bb[4] = {Bv.x, Bv.y, Bv.z, Bv.w};
#pragma unroll
          for (int k = 0; k < 4; ++k) {
            int n = n4 * 4 + k;
            h[n] = fmaf(wv[n], h[n], dx * bb[k]);
          }
        }
        xv = nx;
      }
    }
    size_t sb = (((size_t)b * NCH + c) * DI + d) * 32;
    float Wv[NST];
    Wv[0] = exp2f(dts * A2_0);
#pragma unroll
    for (int n = 1; n < NST; ++n)
      Wv[n] = Wv[(n - 1) >> 1] * Wv[n - 1 - ((n - 1) >> 1)];
#pragma unroll
    for (int n = 0; n < NST; ++n) {
      states[sb + n]      = Wv[n];
      states[sb + 16 + n] = h[n];
    }
  } else {
    float A2[NST];
#pragma unroll
    for (int n = 0; n < NST; ++n)
      A2[n] = -__expf(A_log[(size_t)d * NST + n]) * 1.44269504f;
    for (int s = 0; s < CLEN; s += 64) {
      __syncthreads();
      const float* xg = xdbl + (rbase + s) * XDW;
      for (int q = threadIdx.x; q < 64 * XDW; q += 256) sx[q] = xg[q];
      __syncthreads();
#pragma unroll 2
      for (int u = 0; u < 64; ++u) {
        int tn = s + u + 1;
        float nx = 0.f;
        if (tn < CLEN) nx = b2f(xs[(rbase + tn) * DI + d]);
        float dtr = sx[u * XDW];
        float dt = softplus(fmaf(dtr, wdt, bdt));
        dts += dt;
        float dx = dt * xv;
        const float4* Bp = (const float4*)&sx[u * XDW + 4];
#pragma unroll
        for (int n4 = 0; n4 < 4; ++n4) {
          float4 Bv = Bp[n4];
          float bb[4] = {Bv.x, Bv.y, Bv.z, Bv.w};
#pragma unroll
          for (int k = 0; k < 4; ++k) {
            int n = n4 * 4 + k;
            h[n] = fmaf(exp2f(dt * A2[n]), h[n], dx * bb[k]);
          }
        }
        xv = nx;
      }
    }
    size_t sb = (((size_t)b * NCH + c) * DI + d) * 32;
#pragma unroll
    for (int n = 0; n < NST; ++n) {
      states[sb + n]      = exp2f(dts * A2[n]);
      states[sb + 16 + n] = h[n];
    }
  }
}

// ---------------------------------------------------------------------------
// Scan pass 2: compose chunk states sequentially; h_init -> P slot (in place).
// ---------------------------------------------------------------------------
__global__ __launch_bounds__(256) void scan_pass2(float* __restrict__ states)
{
  int t = blockIdx.x * 256 + threadIdx.x;    // 8*2048*16 = 262144
  int n = t & 15, d = (t >> 4) & 2047, b = t >> 15;
  float h = 0.f;
  for (int c = 0; c < NCH; ++c) {
    size_t sb = (((size_t)b * NCH + c) * DI + d) * 32;
    float P  = states[sb + n];
    float h0 = states[sb + 16 + n];
    states[sb + n] = h;          // h_init entering chunk c
    h = fmaf(P, h, h0);
  }
}

// ---------------------------------------------------------------------------
// Scan pass 3: re-scan from h_init; y = C.h + D*x; gate SiLU(z); bf16 in place.
// ONE channel per thread; same FAST-path power-chain trick as pass 1.
// ---------------------------------------------------------------------------
__global__ __launch_bounds__(256) void scan_pass3(
    const float* __restrict__ xdbl, const bf16_t* __restrict__ xz,
    bf16_t* __restrict__ xs, const float* __restrict__ states,
    const float* __restrict__ W_dt, const float* __restrict__ b_dt,
    const float* __restrict__ A_log, const float* __restrict__ Dp)
{
  const int bid = blockIdx.x;
  const int dg = bid & 7, c = (bid >> 3) & 15, b = bid >> 7;
  const int d = dg * 256 + threadIdx.x;

  const float A2_0 = -__expf(A_log[(size_t)d * NST]) * 1.44269504f;
  bool ok = true;
#pragma unroll
  for (int n = 1; n < NST; ++n) {
    float a = -__expf(A_log[(size_t)d * NST + n]) * 1.44269504f;
    ok = ok && (fabsf(a - (float)(n + 1) * A2_0) <= 1e-3f * (float)(n + 1));
  }
  __shared__ int s_ok;
  __shared__ float sx[64 * XDW];
  if (threadIdx.x == 0) s_ok = 1;
  __syncthreads();
  if (!ok) s_ok = 0;
  __syncthreads();
  const bool fast = (s_ok != 0);

  float h[NST];
  size_t sb = (((size_t)b * NCH + c) * DI + d) * 32;
#pragma unroll
  for (int n = 0; n < NST; ++n) h[n] = states[sb + n];
  const float wdt = W_dt[d], bdt = b_dt[d];
  const float Dd = Dp[d];
  const size_t rbase = (size_t)b * LL + c * CLEN;

  float xv = b2f(xs[rbase * DI + d]);
  float zv = b2f(xz[rbase * 4096 + DI + d]);

  if (fast) {
    for (int s = 0; s < CLEN; s += 64) {
      __syncthreads();
      const float* xg = xdbl + (rbase + s) * XDW;
      for (int q = threadIdx.x; q < 64 * XDW; q += 256) sx[q] = xg[q];
      __syncthreads();
#pragma unroll 2
      for (int u = 0; u < 64; ++u) {
        size_t r = rbase + s + u;
        int tn = s + u + 1;
        float nx = 0.f, nz = 0.f;
        if (tn < CLEN) {
          nx = b2f(xs[(rbase + tn) * DI + d]);
          nz = b2f(xz[(rbase + tn) * 4096 + DI + d]);
        }
        float dtr = sx[u * XDW];
        float dt = softplus(fmaf(dtr, wdt, bdt));
        float dx = dt * xv;
        float y = Dd * xv;
        float wv[NST];
        wv[0] = exp2f(dt * A2_0);
#pragma unroll
        for (int n = 1; n < NST; ++n)
          wv[n] = wv[(n - 1) >> 1] * wv[n - 1 - ((n - 1) >> 1)];
        const float4* Bp = (const float4*)&sx[u * XDW + 4];
        const float4* Cp = (const float4*)&sx[u * XDW + 20];
#pragma unroll
        for (int n4 = 0; n4 < 4; ++n4) {
          float4 Bv = Bp[n4];
          float4 Cv = Cp[n4];
          float bb[4] = {Bv.x, Bv.y, Bv.z, Bv.w};
          float cc[4] = {Cv.x, Cv.y, Cv.z, Cv.w};
#pragma unroll
          for (int k = 0; k < 4; ++k) {
            int n = n4 * 4 + k;
            h[n] = fmaf(wv[n], h[n], dx * bb[k]);
            y = fmaf(h[n], cc[k], y);
          }
        }
        xs[r * DI + d] = f2bn(y * silu(zv));
        xv = nx; zv = nz;
      }
    }
  } else {
    float A2[NST];
#pragma unroll
    for (int n = 0; n < NST; ++n)
      A2[n] = -__expf(A_log[(size_t)d * NST + n]) * 1.44269504f;
    for (int s = 0; s < CLEN; s += 64) {
      __syncthreads();
      const float* xg = xdbl + (rbase + s) * XDW;
      for (int q = threadIdx.x; q < 64 * XDW; q += 256) sx[q] = xg[q];
      __syncthreads();
#pragma unroll 2
      for (int u = 0; u < 64; ++u) {
        size_t r = rbase + s + u;
        int tn = s + u + 1;
        float nx = 0.f, nz = 0.f;
        if (tn < CLEN) {
          nx = b2f(xs[(rbase + tn) * DI + d]);
          nz = b2f(xz[(rbase + tn) * 4096 + DI + d]);
        }
        float dtr = sx[u * XDW];
        float dt = softplus(fmaf(dtr, wdt, bdt));
        float dx = dt * xv;
        float y = Dd * xv;
        const float4* Bp = (const float4*)&sx[u * XDW + 4];
        const float4* Cp = (const float4*)&sx[u * XDW + 20];
#pragma unroll
        for (int n4 = 0; n4 < 4; ++n4) {
          float4 Bv = Bp[n4];
          float4 Cv = Cp[n4];
          float bb[4] = {Bv.x, Bv.y, Bv.z, Bv.w};
          float cc[4] = {Cv.x, Cv.y, Cv.z, Cv.w};
#pragma unroll
          for (int k = 0; k < 4; ++k) {
            int n = n4 * 4 + k;
            h[n] = fmaf(exp2f(dt * A2[n]), h[n], dx * bb[k]);
            y = fmaf(h[n], cc[k], y);
          }
        }
        xs[r * DI + d] = f2bn(y * silu(zv));
        xv = nx; zv = nz;
      }
    }
  }
}

// ---------------------------------------------------------------------------
extern "C" void kernel_launch(void* const* d_in, const int* in_sizes, int n_in,
                              void* d_out, int out_size, void* d_ws, size_t ws_size,
                              hipStream_t stream)
{
  const float* x     = (const float*)d_in[0];
  const float* W_in  = (const float*)d_in[1];
  const float* cw    = (const float*)d_in[2];
  const float* cb    = (const float*)d_in[3];
  const float* W_x   = (const float*)d_in[4];
  const float* W_dt  = (const float*)d_in[5];
  const float* b_dt  = (const float*)d_in[6];
  const float* A_log = (const float*)d_in[7];
  const float* Dp    = (const float*)d_in[8];
  const float* W_out = (const float*)d_in[9];
  float* out = (float*)d_out;

  // ws (proven-safe footprint): xz bf16 [16384,4096] | xs bf16 [16384,2048]
  bf16_t* xz = (bf16_t*)d_ws;
  bf16_t* xs = xz + (size_t)MR * 4096;

  // d_out (64 MiB fp32) as phase-disjoint scratch:
  //   conversions: x_bf [0,32M) | Win_bf [32M,40M) | Wx_bf [40M,40.25M)
  //   scan:        states [0,33.6M) | xdbl [33.6M,36M)  (x_bf/Win_bf dead)
  //   GEMM3 output overwrites everything last.
  bf16_t* x_bf    = (bf16_t*)d_out;
  bf16_t* Win_bf  = x_bf + (size_t)MR * DMOD;
  bf16_t* Wx_bf   = Win_bf + (size_t)4096 * DMOD;
  float*  states  = (float*)d_out;
  float*  xdbl    = states + (size_t)BB * NCH * DI * 32;   // 8.39M floats in
  bf16_t* Wout_bf = xz;   // overlays dead xz after scan pass 3

  // 0) operand conversions
  cvt_bf16<<<(MR*DMOD/4 + 255)/256, 256, 0, stream>>>(x, x_bf, MR*DMOD/4);
  cvt_bf16<<<(4096*DMOD/4 + 255)/256, 256, 0, stream>>>(W_in, Win_bf, 4096*DMOD/4);
  cvt_wx<<<(64*DI)/256, 256, 0, stream>>>(W_x, Wx_bf);
  // 1) xz = x @ W_in^T   (M=16384, N=4096, K=1024) bf16 MFMA 256^2 pipeline
  mgemm_big<bf16_t><<<dim3(4096/256, MR/256), 512, 0, stream>>>(x_bf, Win_bf, xz, 4096, DMOD);
  // 2) causal depthwise conv + bias + SiLU -> xs (bf16)
  conv_silu<<<(BB*LL*512)/256, 256, 0, stream>>>(xz, cw, cb, xs);
  // 3) x_dbl (padded rows) = xs @ W_x^T (MFMA)
  xdbl_mfma<<<MR/64, 256, 0, stream>>>(xs, Wx_bf, xdbl);
  // 4) chunked selective scan (3 passes) + D*xs + SiLU(z) gate, in place in xs
  scan_pass1<<<BB*NCH*8, 256, 0, stream>>>(xdbl, xs, W_dt, b_dt, A_log, states);
  scan_pass2<<<(BB*DI*NST)/256, 256, 0, stream>>>(states);
  scan_pass3<<<BB*NCH*8, 256, 0, stream>>>(xdbl, xz, xs, states, W_dt, b_dt, A_log, Dp);
  // 5) W_out -> bf16 (dead xz region), then out = gated @ W_out^T
  cvt_bf16<<<(DMOD*DI/4 + 255)/256, 256, 0, stream>>>(W_out, Wout_bf, DMOD*DI/4);
  // out = gated @ W_out^T  (M=16384, N=1024, K=2048) -> 256 blocks = 1 round
  mgemm_big<float><<<dim3(DMOD/256, MR/256), 512, 0, stream>>>(xs, Wout_bf, out, DMOD, DI);
}

// Round 6
// 695.000 us; speedup vs baseline: 1.3873x; 1.0361x over previous
//
#include <hip/hip_runtime.h>
#include <math.h>

// Problem constants (fixed by the reference)
#define BB    8
#define LL    2048
#define DMOD  1024
#define DI    2048
#define NST   16
#define MR    (BB*LL)   // 16384 rows
// scan chunking
#define NCH   16
#define CLEN  128       // NCH*CLEN == LL
#define XDW   36        // padded xdbl row: [dt, pad,pad,pad, B0..15, C0..15]

typedef unsigned short bf16_t;
typedef __attribute__((ext_vector_type(8))) __bf16 bf16x8;
typedef __attribute__((ext_vector_type(4))) float  f32x4;

__device__ __forceinline__ float b2f(bf16_t u) {
  return __uint_as_float(((unsigned int)u) << 16);
}
// HW bf16 convert (RNE) -- 1 VALU op
__device__ __forceinline__ bf16_t f2bn(float f) {
  __bf16 h = (__bf16)f;
  return *(bf16_t*)&h;
}

__device__ __forceinline__ void cstore(float* p, float v)  { *p = v; }
__device__ __forceinline__ void cstore(bf16_t* p, float v) { *p = f2bn(v); }

// async global->LDS, 16B per lane; LDS dest = wave-uniform base + lane*16
__device__ __forceinline__ void gld16(const bf16_t* g, bf16_t* l) {
  __builtin_amdgcn_global_load_lds(
      (const __attribute__((address_space(1))) unsigned int*)g,
      (__attribute__((address_space(3))) unsigned int*)l, 16, 0, 0);
}

// softplus via 2 HW transcendentals (abs err ~1e-7, fine vs 5.5e-4 budget)
__device__ __forceinline__ float softplus(float x) {
  return (x > 20.f) ? x : __logf(1.f + __expf(x));
}
__device__ __forceinline__ float silu(float z) {
  return z * __builtin_amdgcn_rcpf(1.f + __expf(-z));
}

// ---------------------------------------------------------------------------
// fp32 -> bf16 convert (vectorized x4)
// ---------------------------------------------------------------------------
__global__ __launch_bounds__(256) void cvt_bf16(
    const float* __restrict__ in, bf16_t* __restrict__ out, int n4)
{
  int i = blockIdx.x * 256 + threadIdx.x;
  if (i >= n4) return;
  float4 v = ((const float4*)in)[i];
  ushort4 u;
  u.x = f2bn(v.x); u.y = f2bn(v.y); u.z = f2bn(v.z); u.w = f2bn(v.w);
  ((ushort4*)out)[i] = u;
}

// W_x [33,2048] fp32 -> padded bf16 [64,2048] (rows 33..63 zero)
__global__ __launch_bounds__(256) void cvt_wx(
    const float* __restrict__ W_x, bf16_t* __restrict__ Wx_bf)
{
  int i = blockIdx.x * 256 + threadIdx.x;   // 64*2048 = 131072
  int j = i >> 11;
  Wx_bf[i] = (j < 33) ? f2bn(W_x[i]) : (bf16_t)0;
}

// ---------------------------------------------------------------------------
// Phase-pipelined MFMA GEMM NT (T3+T4+T5) at 96 KB LDS (R4-proven footprint).
// 256x256 tile, k-units of 32, 512 thr (8 waves: 2M x 4N, 128x64 out/wave).
// LDS: 3-buffer rotation, A[3]+B[3] regions of [256][32] bf16 = 96 KB.
// 2 phases per k-unit; each phase: {4-8 ds_read; 2 gld16 stage (2 units
// ahead); s_barrier; lgkmcnt(0); 16 MFMA (setprio-wrapped); barrier}.
// ONE counted vmcnt(4) per unit before its end-barrier: oldest-retire
// semantics force unit u+1's 4 loads landed; wait->barrier = cross-wave.
// Issue order B(v),A(v),B(v+1),... strictly unit-monotone -> count exact.
// Overwrite safety (each staging >=1 barrier after the region's last
// LGKM-completed read):
//   STAGE_B(u+3)@oddP1  hits Bb[u%3]   last read prev evenP1  (2 bar)
//   STAGE_A(u+2)@evenP2 hits Ab[(u-1)%3] last read prev oddP2 (2 bar)
//   STAGE_A(u+3)@oddP2  hits Ab[u%3]   last read evenP2       (1 bar)
//   STAGE_B(u+4)@evenP1 hits Bb[(u+1)%3] last read oddP1      (2 bar)
// Even/odd register sets + unroll-2 keep all frag indexing static (rule 20).
// Chunk-XOR swizzle both-sides (R4: bank conflicts 1.7e7 -> 0).
// Per-acc-element K order unchanged -> bitwise-identical output.
// ---------------------------------------------------------------------------
template <typename TC>
__global__ __launch_bounds__(512) void mgemm_p3(
    const bf16_t* __restrict__ A, const bf16_t* __restrict__ B,
    TC* __restrict__ C, int N, int K)
{
  __shared__ __align__(16) bf16_t lds[49152];   // 96 KB
  const int tid  = threadIdx.x;
  const int wave = tid >> 6;
  const int lane = tid & 63;
  const int m0 = blockIdx.y * 256;
  const int n0 = blockIdx.x * 256;
  const int fr = lane & 15;
  const int quad = lane >> 4;
  const int wm = (wave >> 2) * 128;   // 2 wave-rows
  const int wn = (wave & 3) * 64;     // 4 wave-cols

  // staging: one gld16 line = 512 thr x 16B = 8KB = 128 rows x 32 elems
  const int srow = tid >> 2;
  const int ssw  = (tid & 3) ^ ((srow >> 1) & 3);   // pre-swizzled chunk
  const bf16_t* Asrc = A + (size_t)(m0 + srow) * K + ssw * 8;
  const bf16_t* Bsrc = B + (size_t)(n0 + srow) * K + ssw * 8;
  const size_t r128 = (size_t)128 * K;

  // swizzled ds_read offsets (elements, region-relative [256][32])
  int aoff[8], boff[4];
#pragma unroll
  for (int i = 0; i < 8; ++i) {
    int row = wm + i * 16 + fr;
    aoff[i] = row * 32 + ((quad ^ ((row >> 1) & 3)) * 8);
  }
#pragma unroll
  for (int j = 0; j < 4; ++j) {
    int row = wn + j * 16 + fr;
    boff[j] = row * 32 + ((quad ^ ((row >> 1) & 3)) * 8);
  }

#define AB_(u) (((u) % 3) * 8192)
#define BB_(u) (24576 + ((u) % 3) * 8192)
#define STAGE_A(u) do {                                                    \
    const bf16_t* s_ = Asrc + (size_t)(u) * 32;                            \
    bf16_t* l_ = lds + AB_(u) + wave * 512;                                \
    gld16(s_, l_); gld16(s_ + r128, l_ + 4096);                            \
  } while (0)
#define STAGE_B(u) do {                                                    \
    const bf16_t* s_ = Bsrc + (size_t)(u) * 32;                            \
    bf16_t* l_ = lds + BB_(u) + wave * 512;                                \
    gld16(s_, l_); gld16(s_ + r128, l_ + 4096);                            \
  } while (0)
#define LDA4(dst,u,ib) do {                                                \
    const bf16_t* r_ = lds + AB_(u);                                       \
    _Pragma("unroll")                                                      \
    for (int i_ = 0; i_ < 4; ++i_)                                         \
      dst[i_] = *(const bf16x8*)&r_[aoff[(ib) + i_]];                      \
  } while (0)
#define LDB4(dst,u) do {                                                   \
    const bf16_t* r_ = lds + BB_(u);                                       \
    _Pragma("unroll")                                                      \
    for (int j_ = 0; j_ < 4; ++j_)                                         \
      dst[j_] = *(const bf16x8*)&r_[boff[j_]];                             \
  } while (0)
#define MM16(ar,br,ib) do {                                                \
    __builtin_amdgcn_s_setprio(1);                                         \
    _Pragma("unroll")                                                      \
    for (int i_ = 0; i_ < 4; ++i_)                                         \
      _Pragma("unroll")                                                    \
      for (int j_ = 0; j_ < 4; ++j_)                                       \
        acc[(ib) + i_][j_] = __builtin_amdgcn_mfma_f32_16x16x32_bf16(      \
            ar[i_], br[j_], acc[(ib) + i_][j_], 0, 0, 0);                  \
    __builtin_amdgcn_s_setprio(0);                                         \
  } while (0)
#define BAR()   __builtin_amdgcn_s_barrier()
#define LGKM0() do { asm volatile("s_waitcnt lgkmcnt(0)" ::: "memory");    \
                     __builtin_amdgcn_sched_barrier(0); } while (0)
#define VMBAR(n) asm volatile("s_waitcnt vmcnt(" #n ")\n\ts_barrier" ::: "memory")

  f32x4 acc[8][4];
#pragma unroll
  for (int i = 0; i < 8; ++i)
#pragma unroll
    for (int j = 0; j < 4; ++j) acc[i][j] = (f32x4){0.f, 0.f, 0.f, 0.f};

  // even-unit sets (aC0=a03, aQ0=a47, bC0), odd-unit sets (aC1,aQ1,bC1)
  bf16x8 aC0[4], aQ0[4], bC0[4], aC1[4], aQ1[4], bC1[4];

  const int nu = K >> 5;   // k-units of 32; nu even, >= 4

  // prologue: stage units 0,1; land unit 0; unit0-P1 (reads, no MFMA)
  STAGE_B(0); STAGE_A(0); STAGE_B(1); STAGE_A(1);   // 8 loads
  VMBAR(4);                                          // unit0 landed
  LDA4(aC0, 0, 0); LDB4(bC0, 0);
  STAGE_B(2);
  BAR(); LGKM0(); BAR();

  for (int u = 0; u < nu; u += 2) {
    const bool s2 = (u + 2 < nu), s3 = (u + 3 < nu), s4 = (u + 4 < nu);
    // ---- even P2: read a47[u]; stage A(u+2); MFMA(a03[u],b[u]); vmcnt
    LDA4(aQ0, u, 4);
    if (s2) STAGE_A(u + 2);
    BAR(); LGKM0();
    MM16(aC0, bC0, 0);
    if (s2) VMBAR(4); else VMBAR(0);                 // unit u+1 landed
    // ---- odd P1: read a03[u+1],b[u+1]; stage B(u+3); MFMA(a47[u],b[u])
    LDA4(aC1, u + 1, 0); LDB4(bC1, u + 1);
    if (s3) STAGE_B(u + 3);
    BAR(); LGKM0();
    MM16(aQ0, bC0, 4);
    BAR();
    // ---- odd P2: read a47[u+1]; stage A(u+3); MFMA(a03[u+1],b[u+1]); vmcnt
    LDA4(aQ1, u + 1, 4);
    if (s3) STAGE_A(u + 3);
    BAR(); LGKM0();
    MM16(aC1, bC1, 0);
    if (s3) VMBAR(4); else VMBAR(0);                 // unit u+2 landed
    // ---- next even P1: read a03[u+2],b[u+2]; stage B(u+4); MFMA(a47[u+1],b[u+1])
    if (s2) { LDA4(aC0, u + 2, 0); LDB4(bC0, u + 2); }
    if (s4) STAGE_B(u + 4);
    BAR(); LGKM0();
    MM16(aQ1, bC1, 4);
    BAR();
  }

  // D col = lane&15, row = quad*4 + r (verified mapping)
#pragma unroll
  for (int i = 0; i < 8; ++i)
#pragma unroll
    for (int j = 0; j < 4; ++j) {
#pragma unroll
      for (int r = 0; r < 4; ++r) {
        int grow = m0 + wm + i * 16 + quad * 4 + r;
        int gcol = n0 + wn + j * 16 + fr;
        cstore(&C[(size_t)grow * N + gcol], acc[i][j][r]);
      }
    }
#undef AB_
#undef BB_
#undef STAGE_A
#undef STAGE_B
#undef LDA4
#undef LDB4
#undef MM16
#undef BAR
#undef LGKM0
#undef VMBAR
}

// ---------------------------------------------------------------------------
// x_dbl MFMA GEMM: xdbl[M,36pad] = xs[M,2048] * Wx_bf[64,2048]^T.
// BM=64, BK=64, 4 waves; wave w owns row-tile w, 3 col-tiles. grid = MR/64.
// Output row layout: dt at col 0, B at 4..19, C at 20..35.
// ---------------------------------------------------------------------------
__global__ __launch_bounds__(256) void xdbl_mfma(
    const bf16_t* __restrict__ xs, const bf16_t* __restrict__ Wx_bf,
    float* __restrict__ xdbl)
{
  __shared__ __align__(16) bf16_t As[2 * 64 * 32];
  __shared__ __align__(16) bf16_t Bs[2 * 64 * 32];
  const int tid  = threadIdx.x;
  const int wave = tid >> 6;
  const int lane = tid & 63;
  const int m0 = blockIdx.x * 64;
  const int fr = lane & 15;
  const int quad = lane >> 4;

  const int srow = wave * 16 + (lane >> 2);
  const int scol = (lane & 3) * 8;
  const bf16_t* Ag = xs + (size_t)(m0 + srow) * DI + scol;
  const bf16_t* Bg = Wx_bf + (size_t)srow * DI + scol;
  bf16_t* lA = As + wave * 512;
  bf16_t* lB = Bs + wave * 512;

  f32x4 acc[3];
#pragma unroll
  for (int jt = 0; jt < 3; ++jt) acc[jt] = (f32x4){0.f, 0.f, 0.f, 0.f};

  for (int k0 = 0; k0 < DI; k0 += 64) {
    __syncthreads();
#pragma unroll
    for (int kk = 0; kk < 2; ++kk) {
      gld16(Ag + k0 + kk * 32, lA + kk * 2048);
      gld16(Bg + k0 + kk * 32, lB + kk * 2048);
    }
    __syncthreads();

#pragma unroll
    for (int kk = 0; kk < 2; ++kk) {
      bf16x8 a = *(const bf16x8*)&As[kk * 2048 + (wave * 16 + fr) * 32 + quad * 8];
#pragma unroll
      for (int jt = 0; jt < 3; ++jt) {
        bf16x8 b = *(const bf16x8*)&Bs[kk * 2048 + (jt * 16 + fr) * 32 + quad * 8];
        acc[jt] = __builtin_amdgcn_mfma_f32_16x16x32_bf16(a, b, acc[jt], 0, 0, 0);
      }
    }
  }

#pragma unroll
  for (int jt = 0; jt < 3; ++jt) {
#pragma unroll
    for (int r = 0; r < 4; ++r) {
      int grow = m0 + wave * 16 + quad * 4 + r;
      int j = jt * 16 + fr;
      if (j < 33) {
        int col = (j == 0) ? 0 : (j + 3);
        xdbl[(size_t)grow * XDW + col] = acc[jt][r];
      }
    }
  }
}

// ---------------------------------------------------------------------------
// Causal depthwise conv1d (k=4) + bias + SiLU.  bf16 xz -> bf16 xs.
// ---------------------------------------------------------------------------
__global__ __launch_bounds__(256) void conv_silu(
    const bf16_t* __restrict__ xz, const float* __restrict__ cw,
    const float* __restrict__ cb, bf16_t* __restrict__ xs)
{
  int idx = blockIdx.x * 256 + threadIdx.x;
  int d4 = idx & 511;
  int l  = (idx >> 9) & 2047;
  int b  = idx >> 20;
  int d  = d4 * 4;

  float wch[4][4];
#pragma unroll
  for (int c = 0; c < 4; ++c)
#pragma unroll
    for (int k = 0; k < 4; ++k) wch[c][k] = cw[(d + c) * 4 + k];

  float acc0 = cb[d+0], acc1 = cb[d+1], acc2 = cb[d+2], acc3 = cb[d+3];
  size_t rowbase = ((size_t)b * LL + l) * 4096 + d;
#pragma unroll
  for (int k = 0; k < 4; ++k) {
    if (l - 3 + k >= 0) {
      ushort4 u = *(const ushort4*)(xz + rowbase - (size_t)(3 - k) * 4096);
      acc0 += b2f(u.x) * wch[0][k];
      acc1 += b2f(u.y) * wch[1][k];
      acc2 += b2f(u.z) * wch[2][k];
      acc3 += b2f(u.w) * wch[3][k];
    }
  }
  ushort4 o;
  o.x = f2bn(silu(acc0)); o.y = f2bn(silu(acc1));
  o.z = f2bn(silu(acc2)); o.w = f2bn(silu(acc3));
  *(ushort4*)(xs + ((size_t)b * LL + l) * (size_t)DI + d) = o;
}

// ---------------------------------------------------------------------------
// Scan pass 1: per (b, chunk) scan from h=0; ONE channel per thread.
// grid: 1024 = b(8) x chunk(16) x dgroup(8); thread covers d = dg*256+tid.
// FAST PATH: A[d,n] = -(n+1) => exp2(dt*A2[n]) = w^(n+1), w = exp2(dt*A2_0).
// Verified per thread vs A_log; block-uniform fallback otherwise.
// states: [b][c][d][32] fp32 (0..15 P, 16..31 h_end).
// ---------------------------------------------------------------------------
__global__ __launch_bounds__(256) void scan_pass1(
    const float* __restrict__ xdbl, const bf16_t* __restrict__ xs,
    const float* __restrict__ W_dt, const float* __restrict__ b_dt,
    const float* __restrict__ A_log, float* __restrict__ states)
{
  const int bid = blockIdx.x;
  const int dg = bid & 7, c = (bid >> 3) & 15, b = bid >> 7;
  const int d = dg * 256 + threadIdx.x;

  const float A2_0 = -__expf(A_log[(size_t)d * NST]) * 1.44269504f;
  bool ok = true;
#pragma unroll
  for (int n = 1; n < NST; ++n) {
    float a = -__expf(A_log[(size_t)d * NST + n]) * 1.44269504f;
    ok = ok && (fabsf(a - (float)(n + 1) * A2_0) <= 1e-3f * (float)(n + 1));
  }
  __shared__ int s_ok;
  __shared__ float sx[64 * XDW];
  if (threadIdx.x == 0) s_ok = 1;
  __syncthreads();
  if (!ok) s_ok = 0;           // benign race: only 0 is written
  __syncthreads();
  const bool fast = (s_ok != 0);

  float h[NST];
#pragma unroll
  for (int n = 0; n < NST; ++n) h[n] = 0.f;
  const float wdt = W_dt[d], bdt = b_dt[d];
  float dts = 0.f;
  const size_t rbase = (size_t)b * LL + c * CLEN;
  float xv = b2f(xs[rbase * DI + d]);

  if (fast) {
    for (int s = 0; s < CLEN; s += 64) {
      __syncthreads();
      const float* xg = xdbl + (rbase + s) * XDW;
      for (int q = threadIdx.x; q < 64 * XDW; q += 256) sx[q] = xg[q];
      __syncthreads();
#pragma unroll 2
      for (int u = 0; u < 64; ++u) {
        int tn = s + u + 1;
        float nx = 0.f;
        if (tn < CLEN) nx = b2f(xs[(rbase + tn) * DI + d]);
        float dtr = sx[u * XDW];
        float dt = softplus(fmaf(dtr, wdt, bdt));
        dts += dt;
        float dx = dt * xv;
        float wv[NST];
        wv[0] = exp2f(dt * A2_0);
#pragma unroll
        for (int n = 1; n < NST; ++n)
          wv[n] = wv[(n - 1) >> 1] * wv[n - 1 - ((n - 1) >> 1)];  // w^(n+1), depth 4
        const float4* Bp = (const float4*)&sx[u * XDW + 4];
#pragma unroll
        for (int n4 = 0; n4 < 4; ++n4) {
          float4 Bv = Bp[n4];
          float bb[4] = {Bv.x, Bv.y, Bv.z, Bv.w};
#pragma unroll
          for (int k = 0; k < 4; ++k) {
            int n = n4 * 4 + k;
            h[n] = fmaf(wv[n], h[n], dx * bb[k]);
          }
        }
        xv = nx;
      }
    }
    size_t sb = (((size_t)b * NCH + c) * DI + d) * 32;
    float Wv[NST];
    Wv[0] = exp2f(dts * A2_0);
#pragma unroll
    for (int n = 1; n < NST; ++n)
      Wv[n] = Wv[(n - 1) >> 1] * Wv[n - 1 - ((n - 1) >> 1)];
#pragma unroll
    for (int n = 0; n < NST; ++n) {
      states[sb + n]      = Wv[n];
      states[sb + 16 + n] = h[n];
    }
  } else {
    float A2[NST];
#pragma unroll
    for (int n = 0; n < NST; ++n)
      A2[n] = -__expf(A_log[(size_t)d * NST + n]) * 1.44269504f;
    for (int s = 0; s < CLEN; s += 64) {
      __syncthreads();
      const float* xg = xdbl + (rbase + s) * XDW;
      for (int q = threadIdx.x; q < 64 * XDW; q += 256) sx[q] = xg[q];
      __syncthreads();
#pragma unroll 2
      for (int u = 0; u < 64; ++u) {
        int tn = s + u + 1;
        float nx = 0.f;
        if (tn < CLEN) nx = b2f(xs[(rbase + tn) * DI + d]);
        float dtr = sx[u * XDW];
        float dt = softplus(fmaf(dtr, wdt, bdt));
        dts += dt;
        float dx = dt * xv;
        const float4* Bp = (const float4*)&sx[u * XDW + 4];
#pragma unroll
        for (int n4 = 0; n4 < 4; ++n4) {
          float4 Bv = Bp[n4];
          float bb[4] = {Bv.x, Bv.y, Bv.z, Bv.w};
#pragma unroll
          for (int k = 0; k < 4; ++k) {
            int n = n4 * 4 + k;
            h[n] = fmaf(exp2f(dt * A2[n]), h[n], dx * bb[k]);
          }
        }
        xv = nx;
      }
    }
    size_t sb = (((size_t)b * NCH + c) * DI + d) * 32;
#pragma unroll
    for (int n = 0; n < NST; ++n) {
      states[sb + n]      = exp2f(dts * A2[n]);
      states[sb + 16 + n] = h[n];
    }
  }
}

// ---------------------------------------------------------------------------
// Scan pass 2: compose chunk states sequentially; h_init -> P slot (in place).
// ---------------------------------------------------------------------------
__global__ __launch_bounds__(256) void scan_pass2(float* __restrict__ states)
{
  int t = blockIdx.x * 256 + threadIdx.x;    // 8*2048*16 = 262144
  int n = t & 15, d = (t >> 4) & 2047, b = t >> 15;
  float h = 0.f;
  for (int c = 0; c < NCH; ++c) {
    size_t sb = (((size_t)b * NCH + c) * DI + d) * 32;
    float P  = states[sb + n];
    float h0 = states[sb + 16 + n];
    states[sb + n] = h;          // h_init entering chunk c
    h = fmaf(P, h, h0);
  }
}

// ---------------------------------------------------------------------------
// Scan pass 3: re-scan from h_init; y = C.h + D*x; gate SiLU(z); bf16 in place.
// ONE channel per thread; same FAST-path power-chain trick as pass 1.
// ---------------------------------------------------------------------------
__global__ __launch_bounds__(256) void scan_pass3(
    const float* __restrict__ xdbl, const bf16_t* __restrict__ xz,
    bf16_t* __restrict__ xs, const float* __restrict__ states,
    const float* __restrict__ W_dt, const float* __restrict__ b_dt,
    const float* __restrict__ A_log, const float* __restrict__ Dp)
{
  const int bid = blockIdx.x;
  const int dg = bid & 7, c = (bid >> 3) & 15, b = bid >> 7;
  const int d = dg * 256 + threadIdx.x;

  const float A2_0 = -__expf(A_log[(size_t)d * NST]) * 1.44269504f;
  bool ok = true;
#pragma unroll
  for (int n = 1; n < NST; ++n) {
    float a = -__expf(A_log[(size_t)d * NST + n]) * 1.44269504f;
    ok = ok && (fabsf(a - (float)(n + 1) * A2_0) <= 1e-3f * (float)(n + 1));
  }
  __shared__ int s_ok;
  __shared__ float sx[64 * XDW];
  if (threadIdx.x == 0) s_ok = 1;
  __syncthreads();
  if (!ok) s_ok = 0;
  __syncthreads();
  const bool fast = (s_ok != 0);

  float h[NST];
  size_t sb = (((size_t)b * NCH + c) * DI + d) * 32;
#pragma unroll
  for (int n = 0; n < NST; ++n) h[n] = states[sb + n];
  const float wdt = W_dt[d], bdt = b_dt[d];
  const float Dd = Dp[d];
  const size_t rbase = (size_t)b * LL + c * CLEN;

  float xv = b2f(xs[rbase * DI + d]);
  float zv = b2f(xz[rbase * 4096 + DI + d]);

  if (fast) {
    for (int s = 0; s < CLEN; s += 64) {
      __syncthreads();
      const float* xg = xdbl + (rbase + s) * XDW;
      for (int q = threadIdx.x; q < 64 * XDW; q += 256) sx[q] = xg[q];
      __syncthreads();
#pragma unroll 2
      for (int u = 0; u < 64; ++u) {
        size_t r = rbase + s + u;
        int tn = s + u + 1;
        float nx = 0.f, nz = 0.f;
        if (tn < CLEN) {
          nx = b2f(xs[(rbase + tn) * DI + d]);
          nz = b2f(xz[(rbase + tn) * 4096 + DI + d]);
        }
        float dtr = sx[u * XDW];
        float dt = softplus(fmaf(dtr, wdt, bdt));
        float dx = dt * xv;
        float y = Dd * xv;
        float wv[NST];
        wv[0] = exp2f(dt * A2_0);
#pragma unroll
        for (int n = 1; n < NST; ++n)
          wv[n] = wv[(n - 1) >> 1] * wv[n - 1 - ((n - 1) >> 1)];
        const float4* Bp = (const float4*)&sx[u * XDW + 4];
        const float4* Cp = (const float4*)&sx[u * XDW + 20];
#pragma unroll
        for (int n4 = 0; n4 < 4; ++n4) {
          float4 Bv = Bp[n4];
          float4 Cv = Cp[n4];
          float bb[4] = {Bv.x, Bv.y, Bv.z, Bv.w};
          float cc[4] = {Cv.x, Cv.y, Cv.z, Cv.w};
#pragma unroll
          for (int k = 0; k < 4; ++k) {
            int n = n4 * 4 + k;
            h[n] = fmaf(wv[n], h[n], dx * bb[k]);
            y = fmaf(h[n], cc[k], y);
          }
        }
        xs[r * DI + d] = f2bn(y * silu(zv));
        xv = nx; zv = nz;
      }
    }
  } else {
    float A2[NST];
#pragma unroll
    for (int n = 0; n < NST; ++n)
      A2[n] = -__expf(A_log[(size_t)d * NST + n]) * 1.44269504f;
    for (int s = 0; s < CLEN; s += 64) {
      __syncthreads();
      const float* xg = xdbl + (rbase + s) * XDW;
      for (int q = threadIdx.x; q < 64 * XDW; q += 256) sx[q] = xg[q];
      __syncthreads();
#pragma unroll 2
      for (int u = 0; u < 64; ++u) {
        size_t r = rbase + s + u;
        int tn = s + u + 1;
        float nx = 0.f, nz = 0.f;
        if (tn < CLEN) {
          nx = b2f(xs[(rbase + tn) * DI + d]);
          nz = b2f(xz[(rbase + tn) * 4096 + DI + d]);
        }
        float dtr = sx[u * XDW];
        float dt = softplus(fmaf(dtr, wdt, bdt));
        float dx = dt * xv;
        float y = Dd * xv;
        const float4* Bp = (const float4*)&sx[u * XDW + 4];
        const float4* Cp = (const float4*)&sx[u * XDW + 20];
#pragma unroll
        for (int n4 = 0; n4 < 4; ++n4) {
          float4 Bv = Bp[n4];
          float4 Cv = Cp[n4];
          float bb[4] = {Bv.x, Bv.y, Bv.z, Bv.w};
          float cc[4] = {Cv.x, Cv.y, Cv.z, Cv.w};
#pragma unroll
          for (int k = 0; k < 4; ++k) {
            int n = n4 * 4 + k;
            h[n] = fmaf(exp2f(dt * A2[n]), h[n], dx * bb[k]);
            y = fmaf(h[n], cc[k], y);
          }
        }
        xs[r * DI + d] = f2bn(y * silu(zv));
        xv = nx; zv = nz;
      }
    }
  }
}

// ---------------------------------------------------------------------------
extern "C" void kernel_launch(void* const* d_in, const int* in_sizes, int n_in,
                              void* d_out, int out_size, void* d_ws, size_t ws_size,
                              hipStream_t stream)
{
  const float* x     = (const float*)d_in[0];
  const float* W_in  = (const float*)d_in[1];
  const float* cw    = (const float*)d_in[2];
  const float* cb    = (const float*)d_in[3];
  const float* W_x   = (const float*)d_in[4];
  const float* W_dt  = (const float*)d_in[5];
  const float* b_dt  = (const float*)d_in[6];
  const float* A_log = (const float*)d_in[7];
  const float* Dp    = (const float*)d_in[8];
  const float* W_out = (const float*)d_in[9];
  float* out = (float*)d_out;

  // ws (proven-safe footprint): xz bf16 [16384,4096] | xs bf16 [16384,2048]
  bf16_t* xz = (bf16_t*)d_ws;
  bf16_t* xs = xz + (size_t)MR * 4096;

  // d_out (64 MiB fp32) as phase-disjoint scratch:
  //   conversions: x_bf [0,32M) | Win_bf [32M,40M) | Wx_bf [40M,40.25M)
  //   scan:        states [0,33.6M) | xdbl [33.6M,36M)  (x_bf/Win_bf dead)
  //   GEMM3 output overwrites everything last.
  bf16_t* x_bf    = (bf16_t*)d_out;
  bf16_t* Win_bf  = x_bf + (size_t)MR * DMOD;
  bf16_t* Wx_bf   = Win_bf + (size_t)4096 * DMOD;
  float*  states  = (float*)d_out;
  float*  xdbl    = states + (size_t)BB * NCH * DI * 32;   // 8.39M floats in
  bf16_t* Wout_bf = xz;   // overlays dead xz after scan pass 3

  // 0) operand conversions
  cvt_bf16<<<(MR*DMOD/4 + 255)/256, 256, 0, stream>>>(x, x_bf, MR*DMOD/4);
  cvt_bf16<<<(4096*DMOD/4 + 255)/256, 256, 0, stream>>>(W_in, Win_bf, 4096*DMOD/4);
  cvt_wx<<<(64*DI)/256, 256, 0, stream>>>(W_x, Wx_bf);
  // 1) xz = x @ W_in^T   (M=16384, N=4096, K=1024) phase-pipelined 256^2
  mgemm_p3<bf16_t><<<dim3(4096/256, MR/256), 512, 0, stream>>>(x_bf, Win_bf, xz, 4096, DMOD);
  // 2) causal depthwise conv + bias + SiLU -> xs (bf16)
  conv_silu<<<(BB*LL*512)/256, 256, 0, stream>>>(xz, cw, cb, xs);
  // 3) x_dbl (padded rows) = xs @ W_x^T (MFMA)
  xdbl_mfma<<<MR/64, 256, 0, stream>>>(xs, Wx_bf, xdbl);
  // 4) chunked selective scan (3 passes) + D*xs + SiLU(z) gate, in place in xs
  scan_pass1<<<BB*NCH*8, 256, 0, stream>>>(xdbl, xs, W_dt, b_dt, A_log, states);
  scan_pass2<<<(BB*DI*NST)/256, 256, 0, stream>>>(states);
  scan_pass3<<<BB*NCH*8, 256, 0, stream>>>(xdbl, xz, xs, states, W_dt, b_dt, A_log, Dp);
  // 5) W_out -> bf16 (dead xz region), then out = gated @ W_out^T
  cvt_bf16<<<(DMOD*DI/4 + 255)/256, 256, 0, stream>>>(W_out, Wout_bf, DMOD*DI/4);
  // out = gated @ W_out^T  (M=16384, N=1024, K=2048)
  mgemm_p3<float><<<dim3(DMOD/256, MR/256), 512, 0, stream>>>(xs, Wout_bf, out, DMOD, DI);
}